// Round 4
// baseline (3872.589 us; speedup 1.0000x reference)
//
#include <hip/hip_runtime.h>

// NeuralMemory scan: B=4, S=256, H=128, EXP=2, DEPTH=2.
// p_t = p0*(1-a_t) + m_t -> params never materialized; momentum m and p0 live
// in REGISTERS (256 VGPRs/lane forced via amdgpu_waves_per_eu(2,2) -- round 3
// shipped with VGPR_Count=128, i.e. p0 was re-loaded from memory every use).
// Cross-WG exchange: 64-bit words (hi=seq tag, lo=payload), relaxed
// agent-scope atomics, readers poll data words directly. Blocks remapped so
// all 4 WGs of a batch land on one XCD if dispatch round-robins by blockIdx
// (perf heuristic only; correctness placement-independent).

constexpr int HD  = 128;   // H
constexpr int SEQ = 256;   // S
constexpr int NB  = 4;     // B
constexpr int ED  = 256;   // H*EXP
constexpr int CW  = 64;    // hidden units per WG per layer (ED/NWG)
constexpr int NWG = 4;     // workgroups per batch

__device__ __forceinline__ float sigm(float x){ return 1.0f/(1.0f+__expf(-x)); }

// ---------------- kernel 1: q/k/v + gate scalars ----------------
__global__ __launch_bounds__(128) void qkv_kernel(
    const float* __restrict__ x,
    const float* __restrict__ Wq, const float* __restrict__ Wk, const float* __restrict__ Wv,
    const float* __restrict__ w_lr, const float* __restrict__ b_lr,
    const float* __restrict__ w_fg, const float* __restrict__ b_fg,
    const float* __restrict__ w_mo, const float* __restrict__ b_mo,
    float* __restrict__ qb, float* __restrict__ kb, float* __restrict__ vb,
    float* __restrict__ thb, float* __restrict__ alb, float* __restrict__ etb)
{
  const int bs = blockIdx.x;          // b*SEQ + s
  const int o  = threadIdx.x;         // 0..127
  __shared__ float xl[HD];
  __shared__ float rb[HD];
  xl[o] = x[(size_t)bs*HD + o];
  __syncthreads();

  float aq=0.f, ak=0.f, av=0.f;
  #pragma unroll 8
  for (int i=0;i<HD;i++){
    float xi = xl[i];
    aq = fmaf(xi, Wq[i*HD+o], aq);
    ak = fmaf(xi, Wk[i*HD+o], ak);
    av = fmaf(xi, Wv[i*HD+o], av);
  }
  float sq_ = aq*sigm(aq);
  float sk_ = ak*sigm(ak);
  float sv_ = av*sigm(av);

  auto bsum = [&](float v)->float {
    rb[o] = v; __syncthreads();
    for (int st=64; st>0; st>>=1){
      if (o < st) rb[o] += rb[o+st];
      __syncthreads();
    }
    float r = rb[0];
    __syncthreads();
    return r;
  };

  float nq = bsum(sq_*sq_);
  float nk = bsum(sk_*sk_);
  float dl = bsum(xl[o]*w_lr[o]);
  float df = bsum(xl[o]*w_fg[o]);
  float dm = bsum(xl[o]*w_mo[o]);

  qb[(size_t)bs*HD+o] = sq_ / fmaxf(sqrtf(nq), 1e-12f);
  kb[(size_t)bs*HD+o] = sk_ / fmaxf(sqrtf(nk), 1e-12f);
  vb[(size_t)bs*HD+o] = sv_;
  if (o==0){
    thb[bs] = sigm(dl + b_lr[0]) * 0.01f;   // MAX_LR
    alb[bs] = sigm(df + b_fg[0]);
    etb[bs] = sigm(dm + b_mo[0]);
  }
}

// ---------------- kernel 2: the sequential scan ----------------
__global__
__attribute__((amdgpu_flat_work_group_size(512, 512), amdgpu_waves_per_eu(2, 2)))
void scan_kernel(
    const float* __restrict__ w1_0g, const float* __restrict__ b1_0g,
    const float* __restrict__ w2_0g, const float* __restrict__ b2_0g,
    const float* __restrict__ mw1_0g, const float* __restrict__ mb1_0g,
    const float* __restrict__ mw2_0g, const float* __restrict__ mb2_0g,
    const float* __restrict__ w1_1g, const float* __restrict__ b1_1g,
    const float* __restrict__ w2_1g, const float* __restrict__ b2_1g,
    const float* __restrict__ mw1_1g, const float* __restrict__ mb1_1g,
    const float* __restrict__ mw2_1g, const float* __restrict__ mb2_1g,
    const float* __restrict__ qbuf, const float* __restrict__ kbuf, const float* __restrict__ vbuf,
    const float* __restrict__ thb, const float* __restrict__ alb, const float* __restrict__ etb,
    unsigned long long* __restrict__ red, float* __restrict__ out)
{
  // XCD-affinity remap: if dispatch round-robins XCDs by blockIdx (%8), all
  // 4 WGs of batch b land on XCD b. Blocks with xcd>=NB exit immediately.
  const int xcd  = blockIdx.x & 7;
  const int slot = blockIdx.x >> 3;   // 0..3
  if (xcd >= NB) return;
  const int b   = xcd;
  const int wg  = slot;
  const int tid = threadIdx.x;
  const int iG  = tid & 31;    // i-group (w1) / o-group (w2)
  const int jG  = tid >> 5;    // j-group 0..15
  const int i0  = iG*4;
  const int j0  = jG*4;
  const int c0  = wg*CW;

  // ---- register-resident parameter slices: 64 m + 64 p0 per thread ----
  float mw1[2][16], pw1[2][16], mw2[2][16], pw2[2][16];
  {
    const float* w1s[2]  = {w1_0g,  w1_1g};
    const float* mw1s[2] = {mw1_0g, mw1_1g};
    const float* w2s[2]  = {w2_0g,  w2_1g};
    const float* mw2s[2] = {mw2_0g, mw2_1g};
    #pragma unroll
    for (int l=0;l<2;l++){
      #pragma unroll
      for (int jj=0;jj<4;jj++){
        #pragma unroll
        for (int ii=0;ii<4;ii++){
          int gi1 = (i0+ii)*ED + (c0+j0+jj);
          pw1[l][jj*4+ii] = w1s[l][gi1];
          mw1[l][jj*4+ii] = mw1s[l][gi1];
          int gi2 = (c0+j0+jj)*HD + (i0+ii);
          pw2[l][jj*4+ii] = w2s[l][gi2];
          mw2[l][jj*4+ii] = mw2s[l][gi2];
        }
      }
    }
  }

  __shared__ float kvec[HD], qvec[HD], vvec[HD];
  __shared__ float u1k[CW], u2k[CW], s1k[CW], s2k[CW], sq1[CW], sq2[CW];
  __shared__ float h1k[HD], h1q[HD], h2k[HD];
  __shared__ float g2v[HD], gh1[HD], gu1[CW], gu2[CW];
  __shared__ float redbuf[8][256];
  __shared__ float b1p[2][CW], b1m[2][CW], b2p[2][32], b2m[2][32];
  __shared__ float scal[8];   // [0]=theta [1]=alpha [2]=eta [5]=cA [6]=cB

  if (tid < CW){
    b1p[0][tid] = b1_0g[c0+tid]; b1m[0][tid] = mb1_0g[c0+tid];
    b1p[1][tid] = b1_1g[c0+tid]; b1m[1][tid] = mb1_1g[c0+tid];
  } else if (tid < CW+32){
    int oo = tid - CW;
    b2p[0][oo] = b2_0g[wg*32+oo]; b2m[0][oo] = mb2_0g[wg*32+oo];
    b2p[1][oo] = b2_1g[wg*32+oo]; b2m[1][oo] = mb2_1g[wg*32+oo];
  }

  // publish: one 64-bit word = (seq<<32) | float bits.  relaxed agent scope.
  auto pubstore = [&](int type, unsigned seq, int idx, float val){
    unsigned long long* p = red + (((b*3+type)*NWG + wg)*256 + idx);
    unsigned long long pk = ((unsigned long long)seq << 32) |
                            (unsigned long long)__float_as_uint(val);
    __hip_atomic_store(p, pk, __ATOMIC_RELAXED, __HIP_MEMORY_SCOPE_AGENT);
  };
  // poll the 3 remote WGs' words for this idx until tag==seq; sum payloads.
  auto pollacc = [&](int type, unsigned seq, int idx, float own)->float{
    unsigned long long* base = red + ((b*3+type)*NWG)*256;
    const int wA=((wg+1)&3)*256+idx, wB=((wg+2)&3)*256+idx, wC=((wg+3)&3)*256+idx;
    unsigned long long vA = __hip_atomic_load(base+wA, __ATOMIC_RELAXED, __HIP_MEMORY_SCOPE_AGENT);
    unsigned long long vB = __hip_atomic_load(base+wB, __ATOMIC_RELAXED, __HIP_MEMORY_SCOPE_AGENT);
    unsigned long long vC = __hip_atomic_load(base+wC, __ATOMIC_RELAXED, __HIP_MEMORY_SCOPE_AGENT);
    float s = own; unsigned got = 0;
    while (got != 7u){
      if (!(got&1u)){
        if ((unsigned)(vA>>32)==seq){ s += __uint_as_float((unsigned)vA); got|=1u; }
        else vA = __hip_atomic_load(base+wA, __ATOMIC_RELAXED, __HIP_MEMORY_SCOPE_AGENT);
      }
      if (!(got&2u)){
        if ((unsigned)(vB>>32)==seq){ s += __uint_as_float((unsigned)vB); got|=2u; }
        else vB = __hip_atomic_load(base+wB, __ATOMIC_RELAXED, __HIP_MEMORY_SCOPE_AGENT);
      }
      if (!(got&4u)){
        if ((unsigned)(vC>>32)==seq){ s += __uint_as_float((unsigned)vC); got|=4u; }
        else vC = __hip_atomic_load(base+wC, __ATOMIC_RELAXED, __HIP_MEMORY_SCOPE_AGENT);
      }
    }
    return s;
  };

  // merged forward of q_t (output) and k_{t+1}
  auto fwdDual = [&](int t, bool writeOut, unsigned seq){
    float cA = scal[5], cB = scal[6];
    // ---- layer0 u ----
    {
      float aq[4]={0,0,0,0}, ak[4]={0,0,0,0};
      #pragma unroll
      for (int ii=0;ii<4;ii++){
        float qi = qvec[i0+ii], ki = kvec[i0+ii];
        #pragma unroll
        for (int jj=0;jj<4;jj++){
          float w = fmaf(pw1[0][jj*4+ii], cA, mw1[0][jj*4+ii]*cB);
          aq[jj] = fmaf(qi, w, aq[jj]);
          ak[jj] = fmaf(ki, w, ak[jj]);
        }
      }
      #pragma unroll
      for (int d=1; d<32; d<<=1){
        #pragma unroll
        for (int jj=0;jj<4;jj++){
          aq[jj] += __shfl_xor(aq[jj], d, 64);
          ak[jj] += __shfl_xor(ak[jj], d, 64);
        }
      }
      if (iG==0){
        #pragma unroll
        for (int jj=0;jj<4;jj++){
          int j=j0+jj;
          float bb = fmaf(b1p[0][j], cA, b1m[0][j]*cB);
          float uq = aq[jj]+bb, uk = ak[jj]+bb;
          u1k[j]=uk; s1k[j]=uk*sigm(uk); sq1[j]=uq*sigm(uq);
        }
      }
    }
    __syncthreads();
    // ---- layer0 s@w2 partials ----
    {
      float aq[4]={0,0,0,0}, ak[4]={0,0,0,0};
      #pragma unroll
      for (int jj=0;jj<4;jj++){
        float sjq = sq1[j0+jj], sjk = s1k[j0+jj];
        #pragma unroll
        for (int oo=0;oo<4;oo++){
          float w = fmaf(pw2[0][jj*4+oo], cA, mw2[0][jj*4+oo]*cB);
          aq[oo] = fmaf(sjq, w, aq[oo]);
          ak[oo] = fmaf(sjk, w, ak[oo]);
        }
      }
      #pragma unroll
      for (int oo=0;oo<4;oo++){
        aq[oo] += __shfl_xor(aq[oo], 32, 64);
        ak[oo] += __shfl_xor(ak[oo], 32, 64);
      }
      if ((tid & 32)==0){
        int wv = tid>>6;
        #pragma unroll
        for (int oo=0;oo<4;oo++){
          redbuf[wv][i0+oo]     = aq[oo];
          redbuf[wv][128+i0+oo] = ak[oo];
        }
      }
    }
    __syncthreads();
    if (tid < 256){
      float p=0.f;
      #pragma unroll
      for (int w_=0; w_<8; w_++) p += redbuf[w_][tid];
      int o = tid & 127;
      if (o >= wg*32 && o < wg*32+32){
        int oo = o - wg*32;
        p += fmaf(b2p[0][oo], cA, b2m[0][oo]*cB);   // owner adds b2 shard
      }
      pubstore(1, seq, tid, p);
      float s0 = ((tid<128) ? qvec[o] : kvec[o]) + pollacc(1, seq, tid, p);
      if (tid<128) h1q[o]=s0; else h1k[o]=s0;
    }
    __syncthreads();
    // ---- layer1 u ----
    {
      float aq[4]={0,0,0,0}, ak[4]={0,0,0,0};
      #pragma unroll
      for (int ii=0;ii<4;ii++){
        float qi = h1q[i0+ii], ki = h1k[i0+ii];
        #pragma unroll
        for (int jj=0;jj<4;jj++){
          float w = fmaf(pw1[1][jj*4+ii], cA, mw1[1][jj*4+ii]*cB);
          aq[jj] = fmaf(qi, w, aq[jj]);
          ak[jj] = fmaf(ki, w, ak[jj]);
        }
      }
      #pragma unroll
      for (int d=1; d<32; d<<=1){
        #pragma unroll
        for (int jj=0;jj<4;jj++){
          aq[jj] += __shfl_xor(aq[jj], d, 64);
          ak[jj] += __shfl_xor(ak[jj], d, 64);
        }
      }
      if (iG==0){
        #pragma unroll
        for (int jj=0;jj<4;jj++){
          int j=j0+jj;
          float bb = fmaf(b1p[1][j], cA, b1m[1][j]*cB);
          float uq = aq[jj]+bb, uk = ak[jj]+bb;
          u2k[j]=uk; s2k[j]=uk*sigm(uk); sq2[j]=uq*sigm(uq);
        }
      }
    }
    __syncthreads();
    // ---- layer1 s@w2 partials ----
    {
      float aq[4]={0,0,0,0}, ak[4]={0,0,0,0};
      #pragma unroll
      for (int jj=0;jj<4;jj++){
        float sjq = sq2[j0+jj], sjk = s2k[j0+jj];
        #pragma unroll
        for (int oo=0;oo<4;oo++){
          float w = fmaf(pw2[1][jj*4+oo], cA, mw2[1][jj*4+oo]*cB);
          aq[oo] = fmaf(sjq, w, aq[oo]);
          ak[oo] = fmaf(sjk, w, ak[oo]);
        }
      }
      #pragma unroll
      for (int oo=0;oo<4;oo++){
        aq[oo] += __shfl_xor(aq[oo], 32, 64);
        ak[oo] += __shfl_xor(ak[oo], 32, 64);
      }
      if ((tid & 32)==0){
        int wv = tid>>6;
        #pragma unroll
        for (int oo=0;oo<4;oo++){
          redbuf[wv][i0+oo]     = aq[oo];
          redbuf[wv][128+i0+oo] = ak[oo];
        }
      }
    }
    __syncthreads();
    if (tid < 256){
      float p=0.f;
      #pragma unroll
      for (int w_=0; w_<8; w_++) p += redbuf[w_][tid];
      int o = tid & 127;
      if (o >= wg*32 && o < wg*32+32){
        int oo = o - wg*32;
        p += fmaf(b2p[1][oo], cA, b2m[1][oo]*cB);
      }
      pubstore(2, seq, tid, p);
      float s0 = ((tid<128) ? h1q[o] : h1k[o]) + pollacc(2, seq, tid, p);
      if (tid<128){
        if (writeOut && o >= wg*32 && o < wg*32+32)
          out[((size_t)(b*SEQ + t))*HD + o] = s0;   // y[b,t,:] shard
      } else {
        h2k[o] = s0;                                 // pred for next bwd
      }
    }
  };

  // ---- prologue: forward k_0 with cp = p0 exactly (cA=1, cB=0) ----
  if (tid < HD){
    kvec[tid] = kbuf[((size_t)b*SEQ + 0)*HD + tid];
    qvec[tid] = 0.f;
  }
  if (tid==0){ scal[5]=1.f; scal[6]=0.f; }
  __syncthreads();
  fwdDual(0, false, 1u);

  for (int t=0; t<SEQ; ++t){
    if (tid < HD) vvec[tid] = vbuf[((size_t)b*SEQ + t)*HD + tid];
    if (tid==0){
      scal[0]=thb[b*SEQ+t]; scal[1]=alb[b*SEQ+t]; scal[2]=etb[b*SEQ+t];
    }
    __syncthreads();
    float cAp = scal[5], cBp = scal[6];   // coefs of p_{t-1} (prev fwd)
    if (tid < HD) g2v[tid] = (2.0f/128.0f)*(h2k[tid]-vvec[tid]);
    __syncthreads();
    // gu2 = (g2 @ w2b^T) * silu'(u2)
    {
      float acc[4]={0,0,0,0};
      #pragma unroll
      for (int oo=0;oo<4;oo++){
        float go = g2v[i0+oo];
        #pragma unroll
        for (int jj=0;jj<4;jj++){
          float w = fmaf(pw2[1][jj*4+oo], cAp, mw2[1][jj*4+oo]*cBp);
          acc[jj] = fmaf(go, w, acc[jj]);
        }
      }
      #pragma unroll
      for (int d=1; d<32; d<<=1){
        #pragma unroll
        for (int jj=0;jj<4;jj++) acc[jj] += __shfl_xor(acc[jj], d, 64);
      }
      if (iG==0){
        #pragma unroll
        for (int jj=0;jj<4;jj++){
          int j=j0+jj; float u=u2k[j]; float sg=sigm(u);
          gu2[j] = acc[jj]*sg*fmaf(u, 1.f-sg, 1.f);
        }
      }
    }
    __syncthreads();
    // gh1 partial = gu2 @ w1b^T  (cross-WG exchange, type 0)
    {
      float acc[4]={0,0,0,0};
      #pragma unroll
      for (int jj=0;jj<4;jj++){
        float gj = gu2[j0+jj];
        #pragma unroll
        for (int ii=0;ii<4;ii++){
          float w = fmaf(pw1[1][jj*4+ii], cAp, mw1[1][jj*4+ii]*cBp);
          acc[ii] = fmaf(gj, w, acc[ii]);
        }
      }
      #pragma unroll
      for (int ii=0;ii<4;ii++) acc[ii] += __shfl_xor(acc[ii], 32, 64);
      if ((tid & 32)==0){
        int wv = tid>>6;
        #pragma unroll
        for (int ii=0;ii<4;ii++) redbuf[wv][i0+ii] = acc[ii];
      }
    }
    __syncthreads();
    {
      unsigned seqB = (unsigned)(t+1);
      if (tid < HD){
        float p=0.f;
        #pragma unroll
        for (int w_=0;w_<8;w_++) p += redbuf[w_][tid];
        pubstore(0, seqB, tid, p);
        gh1[tid] = g2v[tid] + pollacc(0, seqB, tid, p);
      }
    }
    __syncthreads();
    // gu1 = (gh1 @ w2a^T) * silu'(u1)
    {
      float acc[4]={0,0,0,0};
      #pragma unroll
      for (int oo=0;oo<4;oo++){
        float go = gh1[i0+oo];
        #pragma unroll
        for (int jj=0;jj<4;jj++){
          float w = fmaf(pw2[0][jj*4+oo], cAp, mw2[0][jj*4+oo]*cBp);
          acc[jj] = fmaf(go, w, acc[jj]);
        }
      }
      #pragma unroll
      for (int d=1; d<32; d<<=1){
        #pragma unroll
        for (int jj=0;jj<4;jj++) acc[jj] += __shfl_xor(acc[jj], d, 64);
      }
      if (iG==0){
        #pragma unroll
        for (int jj=0;jj<4;jj++){
          int j=j0+jj; float u=u1k[j]; float sg=sigm(u);
          gu1[j] = acc[jj]*sg*fmaf(u, 1.f-sg, 1.f);
        }
      }
    }
    __syncthreads();
    // ---- momentum update: m = eta*m - theta*grad (grads are outer products) ----
    {
      float th = scal[0], et = scal[2];
      #pragma unroll
      for (int jj=0;jj<4;jj++){
        float g1j = gu1[j0+jj], g2j = gu2[j0+jj];
        float s1j = s1k[j0+jj], s2j = s2k[j0+jj];
        #pragma unroll
        for (int ii=0;ii<4;ii++){
          int e = jj*4+ii;
          mw1[0][e] = fmaf(et, mw1[0][e], -th*(kvec[i0+ii]*g1j));
          mw1[1][e] = fmaf(et, mw1[1][e], -th*(h1k[i0+ii]*g2j));
          mw2[0][e] = fmaf(et, mw2[0][e], -th*(s1j*gh1[i0+ii]));
          mw2[1][e] = fmaf(et, mw2[1][e], -th*(s2j*g2v[i0+ii]));
        }
      }
      if (tid < CW){
        b1m[0][tid] = fmaf(et, b1m[0][tid], -th*gu1[tid]);
        b1m[1][tid] = fmaf(et, b1m[1][tid], -th*gu2[tid]);
      } else if (tid < CW+32){
        int oo = tid - CW;
        b2m[0][oo] = fmaf(et, b2m[0][oo], -th*gh1[wg*32+oo]);
        b2m[1][oo] = fmaf(et, b2m[1][oo], -th*g2v[wg*32+oo]);
      }
    }
    __syncthreads();
    // ---- merged forward: q_t (output) + k_{t+1}, p_t = p0*(1-a_t) + m_t ----
    if (tid < HD){
      qvec[tid] = qbuf[((size_t)b*SEQ + t)*HD + tid];
      int tn = (t < SEQ-1) ? t+1 : SEQ-1;
      kvec[tid] = kbuf[((size_t)b*SEQ + tn)*HD + tid];
    }
    if (tid==0){ scal[5] = 1.f - scal[1]; scal[6] = 1.f; }
    __syncthreads();
    fwdDual(t, true, (unsigned)(t+2));
  }
}

extern "C" void kernel_launch(void* const* d_in, const int* in_sizes, int n_in,
                              void* d_out, int out_size, void* d_ws, size_t ws_size,
                              hipStream_t stream)
{
  (void)in_sizes; (void)n_in; (void)out_size; (void)ws_size;
  const float* x    = (const float*)d_in[0];
  const float* Wq   = (const float*)d_in[1];
  const float* Wk   = (const float*)d_in[2];
  const float* Wv   = (const float*)d_in[3];
  const float* w_lr = (const float*)d_in[4];
  const float* b_lr = (const float*)d_in[5];
  const float* w_fg = (const float*)d_in[6];
  const float* b_fg = (const float*)d_in[7];
  const float* w_mo = (const float*)d_in[8];
  const float* b_mo = (const float*)d_in[9];
  const float* w1_0 = (const float*)d_in[10];
  const float* b1_0 = (const float*)d_in[11];
  const float* w2_0 = (const float*)d_in[12];
  const float* b2_0 = (const float*)d_in[13];
  const float* m_w1_0 = (const float*)d_in[14];
  const float* m_b1_0 = (const float*)d_in[15];
  const float* m_w2_0 = (const float*)d_in[16];
  const float* m_b2_0 = (const float*)d_in[17];
  const float* w1_1 = (const float*)d_in[18];
  const float* b1_1 = (const float*)d_in[19];
  const float* w2_1 = (const float*)d_in[20];
  const float* b2_1 = (const float*)d_in[21];
  const float* m_w1_1 = (const float*)d_in[22];
  const float* m_b1_1 = (const float*)d_in[23];
  const float* m_w2_1 = (const float*)d_in[24];
  const float* m_b2_1 = (const float*)d_in[25];

  float* wsf = (float*)d_ws;
  // 64-bit tagged exchange slots: 4 batches x 3 types x 4 WGs x 256 words
  unsigned long long* red = (unsigned long long*)d_ws;   // 98304 B
  float* qbuf = wsf + 32768;
  float* kbuf = qbuf + NB*SEQ*HD;
  float* vbuf = kbuf + NB*SEQ*HD;
  float* thb  = vbuf + NB*SEQ*HD;
  float* alb  = thb + NB*SEQ;
  float* etb  = alb + NB*SEQ;
  // No memset needed: ws is re-poisoned to 0xAA before every launch, and
  // 0xAAAAAAAA never equals a valid seq tag (tags are 1..257).

  qkv_kernel<<<dim3(NB*SEQ), dim3(HD), 0, stream>>>(
      x, Wq, Wk, Wv, w_lr, b_lr, w_fg, b_fg, w_mo, b_mo,
      qbuf, kbuf, vbuf, thb, alb, etb);

  // 32 blocks: blockIdx&7 = XCD (heuristic), blockIdx>>3 = wg slot.
  scan_kernel<<<dim3(32), dim3(512), 0, stream>>>(
      w1_0, b1_0, w2_0, b2_0, m_w1_0, m_b1_0, m_w2_0, m_b2_0,
      w1_1, b1_1, w2_1, b2_1, m_w1_1, m_b1_1, m_w2_1, m_b2_1,
      qbuf, kbuf, vbuf, thb, alb, etb,
      red, (float*)d_out);
}

// Round 5
// 3303.342 us; speedup vs baseline: 1.1723x; 1.1723x over previous
//
#include <hip/hip_runtime.h>

// NeuralMemory scan: B=4, S=256, H=128, EXP=2, DEPTH=2.
// p_t = p0*(1-a_t) + m_t. Momentum m in REGISTERS (64 f/thread); p0 in LDS
// swizzled [plane][tid] (each thread reads only its own entries ->
// conflict-free ds_read, no remat-from-global as in rounds 1-4 where the
// allocator kept VGPR=128 and re-fetched p0 every pass). Cross-WG exchange:
// 64-bit tagged words, relaxed agent-scope atomics, direct data-word polling.
// Backward keeps gu1/gu2 in registers post-shfl-butterfly (3 fewer syncs).

constexpr int HD  = 128;   // H
constexpr int SEQ = 256;   // S
constexpr int NB  = 4;     // B
constexpr int ED  = 256;   // H*EXP
constexpr int CW  = 64;    // hidden units per WG per layer (ED/NWG)
constexpr int NWG = 4;     // workgroups per batch

__device__ __forceinline__ float sigm(float x){ return 1.0f/(1.0f+__expf(-x)); }

// ---------------- kernel 1: q/k/v + gate scalars ----------------
__global__ __launch_bounds__(128) void qkv_kernel(
    const float* __restrict__ x,
    const float* __restrict__ Wq, const float* __restrict__ Wk, const float* __restrict__ Wv,
    const float* __restrict__ w_lr, const float* __restrict__ b_lr,
    const float* __restrict__ w_fg, const float* __restrict__ b_fg,
    const float* __restrict__ w_mo, const float* __restrict__ b_mo,
    float* __restrict__ qb, float* __restrict__ kb, float* __restrict__ vb,
    float* __restrict__ thb, float* __restrict__ alb, float* __restrict__ etb)
{
  const int bs = blockIdx.x;          // b*SEQ + s
  const int o  = threadIdx.x;         // 0..127
  __shared__ float xl[HD];
  __shared__ float rb[HD];
  xl[o] = x[(size_t)bs*HD + o];
  __syncthreads();

  float aq=0.f, ak=0.f, av=0.f;
  #pragma unroll 8
  for (int i=0;i<HD;i++){
    float xi = xl[i];
    aq = fmaf(xi, Wq[i*HD+o], aq);
    ak = fmaf(xi, Wk[i*HD+o], ak);
    av = fmaf(xi, Wv[i*HD+o], av);
  }
  float sq_ = aq*sigm(aq);
  float sk_ = ak*sigm(ak);
  float sv_ = av*sigm(av);

  auto bsum = [&](float v)->float {
    rb[o] = v; __syncthreads();
    for (int st=64; st>0; st>>=1){
      if (o < st) rb[o] += rb[o+st];
      __syncthreads();
    }
    float r = rb[0];
    __syncthreads();
    return r;
  };

  float nq = bsum(sq_*sq_);
  float nk = bsum(sk_*sk_);
  float dl = bsum(xl[o]*w_lr[o]);
  float df = bsum(xl[o]*w_fg[o]);
  float dm = bsum(xl[o]*w_mo[o]);

  qb[(size_t)bs*HD+o] = sq_ / fmaxf(sqrtf(nq), 1e-12f);
  kb[(size_t)bs*HD+o] = sk_ / fmaxf(sqrtf(nk), 1e-12f);
  vb[(size_t)bs*HD+o] = sv_;
  if (o==0){
    thb[bs] = sigm(dl + b_lr[0]) * 0.01f;   // MAX_LR
    alb[bs] = sigm(df + b_fg[0]);
    etb[bs] = sigm(dm + b_mo[0]);
  }
}

// ---------------- kernel 2: the sequential scan ----------------
__global__ __launch_bounds__(512, 1) void scan_kernel(
    const float* __restrict__ w1_0g, const float* __restrict__ b1_0g,
    const float* __restrict__ w2_0g, const float* __restrict__ b2_0g,
    const float* __restrict__ mw1_0g, const float* __restrict__ mb1_0g,
    const float* __restrict__ mw2_0g, const float* __restrict__ mb2_0g,
    const float* __restrict__ w1_1g, const float* __restrict__ b1_1g,
    const float* __restrict__ w2_1g, const float* __restrict__ b2_1g,
    const float* __restrict__ mw1_1g, const float* __restrict__ mb1_1g,
    const float* __restrict__ mw2_1g, const float* __restrict__ mb2_1g,
    const float* __restrict__ qbuf, const float* __restrict__ kbuf, const float* __restrict__ vbuf,
    const float* __restrict__ thb, const float* __restrict__ alb, const float* __restrict__ etb,
    unsigned long long* __restrict__ red, float* __restrict__ out)
{
  const int bid = blockIdx.x;
  const int b   = bid & 3;     // batch
  const int wg  = bid >> 2;    // 0..3 within batch
  const int tid = threadIdx.x;
  const int iG  = tid & 31;    // i-group (w1) / o-group (w2)
  const int jG  = tid >> 5;    // j-group 0..15
  const int i0  = iG*4;
  const int j0  = jG*4;
  const int c0  = wg*CW;

  // p0 in LDS, swizzled so each thread reads only [plane][tid] (own writes,
  // conflict-free). m stays in registers (mutable, 64 floats/thread).
  __shared__ float pw1L[2][16][512];   // 64 KB
  __shared__ float pw2L[2][16][512];   // 64 KB
  __shared__ float kvecB[2][HD], qvecB[2][HD];
  __shared__ float u1k[CW], u2k[CW], s1k[CW], s2k[CW], sq1[CW], sq2[CW];
  __shared__ float h1k[HD], h1q[HD], h2k[HD];
  __shared__ float g2v[HD], gh1[HD];
  __shared__ float redbuf[8][256];
  __shared__ float b1p[2][CW], b1m[2][CW], b2p[2][32], b2m[2][32];

  float mw1[2][16], mw2[2][16];
  {
    const float* w1s[2]  = {w1_0g,  w1_1g};
    const float* mw1s[2] = {mw1_0g, mw1_1g};
    const float* w2s[2]  = {w2_0g,  w2_1g};
    const float* mw2s[2] = {mw2_0g, mw2_1g};
    #pragma unroll
    for (int l=0;l<2;l++){
      #pragma unroll
      for (int jj=0;jj<4;jj++){
        #pragma unroll
        for (int ii=0;ii<4;ii++){
          int gi1 = (i0+ii)*ED + (c0+j0+jj);
          pw1L[l][jj*4+ii][tid] = w1s[l][gi1];
          mw1[l][jj*4+ii] = mw1s[l][gi1];
          int gi2 = (c0+j0+jj)*HD + (i0+ii);
          pw2L[l][jj*4+ii][tid] = w2s[l][gi2];
          mw2[l][jj*4+ii] = mw2s[l][gi2];
        }
      }
    }
  }
  if (tid < CW){
    b1p[0][tid] = b1_0g[c0+tid]; b1m[0][tid] = mb1_0g[c0+tid];
    b1p[1][tid] = b1_1g[c0+tid]; b1m[1][tid] = mb1_1g[c0+tid];
  } else if (tid < CW+32){
    int oo = tid - CW;
    b2p[0][oo] = b2_0g[wg*32+oo]; b2m[0][oo] = mb2_0g[wg*32+oo];
    b2p[1][oo] = b2_1g[wg*32+oo]; b2m[1][oo] = mb2_1g[wg*32+oo];
  }

  // publish: one 64-bit word = (seq<<32) | float bits.  relaxed agent scope.
  auto pubstore = [&](int type, unsigned seq, int idx, float val){
    unsigned long long* p = red + (((b*3+type)*NWG + wg)*256 + idx);
    unsigned long long pk = ((unsigned long long)seq << 32) |
                            (unsigned long long)__float_as_uint(val);
    __hip_atomic_store(p, pk, __ATOMIC_RELAXED, __HIP_MEMORY_SCOPE_AGENT);
  };
  auto pollacc = [&](int type, unsigned seq, int idx, float own)->float{
    unsigned long long* base = red + ((b*3+type)*NWG)*256;
    const int wA=((wg+1)&3)*256+idx, wB=((wg+2)&3)*256+idx, wC=((wg+3)&3)*256+idx;
    unsigned long long vA = __hip_atomic_load(base+wA, __ATOMIC_RELAXED, __HIP_MEMORY_SCOPE_AGENT);
    unsigned long long vB = __hip_atomic_load(base+wB, __ATOMIC_RELAXED, __HIP_MEMORY_SCOPE_AGENT);
    unsigned long long vC = __hip_atomic_load(base+wC, __ATOMIC_RELAXED, __HIP_MEMORY_SCOPE_AGENT);
    float s = own; unsigned got = 0;
    while (got != 7u){
      if (!(got&1u)){
        if ((unsigned)(vA>>32)==seq){ s += __uint_as_float((unsigned)vA); got|=1u; }
        else vA = __hip_atomic_load(base+wA, __ATOMIC_RELAXED, __HIP_MEMORY_SCOPE_AGENT);
      }
      if (!(got&2u)){
        if ((unsigned)(vB>>32)==seq){ s += __uint_as_float((unsigned)vB); got|=2u; }
        else vB = __hip_atomic_load(base+wB, __ATOMIC_RELAXED, __HIP_MEMORY_SCOPE_AGENT);
      }
      if (!(got&4u)){
        if ((unsigned)(vC>>32)==seq){ s += __uint_as_float((unsigned)vC); got|=4u; }
        else vC = __hip_atomic_load(base+wC, __ATOMIC_RELAXED, __HIP_MEMORY_SCOPE_AGENT);
      }
    }
    return s;
  };

  // merged forward of q_t (output) and k_{t+1}; bi = k/q buffer parity.
  auto fwdDual = [&](int t, bool writeOut, unsigned seq, int bi, float cA, float cB){
    // ---- layer0 u (fully local: columns owned) ----
    {
      float aq[4]={0,0,0,0}, ak[4]={0,0,0,0};
      #pragma unroll
      for (int ii=0;ii<4;ii++){
        float qi = qvecB[bi][i0+ii], ki = kvecB[bi][i0+ii];
        #pragma unroll
        for (int jj=0;jj<4;jj++){
          float w = fmaf(pw1L[0][jj*4+ii][tid], cA, mw1[0][jj*4+ii]*cB);
          aq[jj] = fmaf(qi, w, aq[jj]);
          ak[jj] = fmaf(ki, w, ak[jj]);
        }
      }
      #pragma unroll
      for (int d=1; d<32; d<<=1){
        #pragma unroll
        for (int jj=0;jj<4;jj++){
          aq[jj] += __shfl_xor(aq[jj], d, 64);
          ak[jj] += __shfl_xor(ak[jj], d, 64);
        }
      }
      if (iG==0){
        #pragma unroll
        for (int jj=0;jj<4;jj++){
          int j=j0+jj;
          float bb = fmaf(b1p[0][j], cA, b1m[0][j]*cB);
          float uq = aq[jj]+bb, uk = ak[jj]+bb;
          u1k[j]=uk; s1k[j]=uk*sigm(uk); sq1[j]=uq*sigm(uq);
        }
      }
    }
    __syncthreads();
    // ---- layer0 s@w2 partials ----
    {
      float aq[4]={0,0,0,0}, ak[4]={0,0,0,0};
      #pragma unroll
      for (int jj=0;jj<4;jj++){
        float sjq = sq1[j0+jj], sjk = s1k[j0+jj];
        #pragma unroll
        for (int oo=0;oo<4;oo++){
          float w = fmaf(pw2L[0][jj*4+oo][tid], cA, mw2[0][jj*4+oo]*cB);
          aq[oo] = fmaf(sjq, w, aq[oo]);
          ak[oo] = fmaf(sjk, w, ak[oo]);
        }
      }
      #pragma unroll
      for (int oo=0;oo<4;oo++){
        aq[oo] += __shfl_xor(aq[oo], 32, 64);
        ak[oo] += __shfl_xor(ak[oo], 32, 64);
      }
      if ((tid & 32)==0){
        int wv = tid>>6;
        #pragma unroll
        for (int oo=0;oo<4;oo++){
          redbuf[wv][i0+oo]     = aq[oo];
          redbuf[wv][128+i0+oo] = ak[oo];
        }
      }
    }
    __syncthreads();
    if (tid < 256){
      float p=0.f;
      #pragma unroll
      for (int w_=0; w_<8; w_++) p += redbuf[w_][tid];
      int o = tid & 127;
      if (o >= wg*32 && o < wg*32+32){
        int oo = o - wg*32;
        p += fmaf(b2p[0][oo], cA, b2m[0][oo]*cB);
      }
      pubstore(1, seq, tid, p);
      float s0 = ((tid<128) ? qvecB[bi][o] : kvecB[bi][o]) + pollacc(1, seq, tid, p);
      if (tid<128) h1q[o]=s0; else h1k[o]=s0;
    }
    __syncthreads();
    // ---- layer1 u ----
    {
      float aq[4]={0,0,0,0}, ak[4]={0,0,0,0};
      #pragma unroll
      for (int ii=0;ii<4;ii++){
        float qi = h1q[i0+ii], ki = h1k[i0+ii];
        #pragma unroll
        for (int jj=0;jj<4;jj++){
          float w = fmaf(pw1L[1][jj*4+ii][tid], cA, mw1[1][jj*4+ii]*cB);
          aq[jj] = fmaf(qi, w, aq[jj]);
          ak[jj] = fmaf(ki, w, ak[jj]);
        }
      }
      #pragma unroll
      for (int d=1; d<32; d<<=1){
        #pragma unroll
        for (int jj=0;jj<4;jj++){
          aq[jj] += __shfl_xor(aq[jj], d, 64);
          ak[jj] += __shfl_xor(ak[jj], d, 64);
        }
      }
      if (iG==0){
        #pragma unroll
        for (int jj=0;jj<4;jj++){
          int j=j0+jj;
          float bb = fmaf(b1p[1][j], cA, b1m[1][j]*cB);
          float uq = aq[jj]+bb, uk = ak[jj]+bb;
          u2k[j]=uk; s2k[j]=uk*sigm(uk); sq2[j]=uq*sigm(uq);
        }
      }
    }
    __syncthreads();
    // ---- layer1 s@w2 partials ----
    {
      float aq[4]={0,0,0,0}, ak[4]={0,0,0,0};
      #pragma unroll
      for (int jj=0;jj<4;jj++){
        float sjq = sq2[j0+jj], sjk = s2k[j0+jj];
        #pragma unroll
        for (int oo=0;oo<4;oo++){
          float w = fmaf(pw2L[1][jj*4+oo][tid], cA, mw2[1][jj*4+oo]*cB);
          aq[oo] = fmaf(sjq, w, aq[oo]);
          ak[oo] = fmaf(sjk, w, ak[oo]);
        }
      }
      #pragma unroll
      for (int oo=0;oo<4;oo++){
        aq[oo] += __shfl_xor(aq[oo], 32, 64);
        ak[oo] += __shfl_xor(ak[oo], 32, 64);
      }
      if ((tid & 32)==0){
        int wv = tid>>6;
        #pragma unroll
        for (int oo=0;oo<4;oo++){
          redbuf[wv][i0+oo]     = aq[oo];
          redbuf[wv][128+i0+oo] = ak[oo];
        }
      }
    }
    __syncthreads();
    if (tid < 256){
      float p=0.f;
      #pragma unroll
      for (int w_=0; w_<8; w_++) p += redbuf[w_][tid];
      int o = tid & 127;
      if (o >= wg*32 && o < wg*32+32){
        int oo = o - wg*32;
        p += fmaf(b2p[1][oo], cA, b2m[1][oo]*cB);
      }
      pubstore(2, seq, tid, p);
      float s0 = ((tid<128) ? h1q[o] : h1k[o]) + pollacc(2, seq, tid, p);
      if (tid<128){
        if (writeOut && o >= wg*32 && o < wg*32+32)
          out[((size_t)(b*SEQ + t))*HD + o] = s0;
      } else {
        h2k[o] = s0;
      }
    }
  };

  // ---- prologue: forward k_0 with cp = p0 exactly (cA=1, cB=0) ----
  if (tid < HD){
    kvecB[0][tid] = kbuf[((size_t)b*SEQ + 0)*HD + tid];
    qvecB[0][tid] = 0.f;
  }
  __syncthreads();
  fwdDual(0, false, 1u, 0, 1.f, 0.f);

  float cAp = 1.f, cBp = 0.f;   // coefs of p_{t-1} (prev fwd), registers
  for (int t=0; t<SEQ; ++t){
    const int cur = t & 1;
    const float th = thb[b*SEQ+t];
    const float al = alb[b*SEQ+t];
    const float et = etb[b*SEQ+t];
    __syncthreads();                    // h2k (F2 of prev fwd) visible
    if (tid < HD)
      g2v[tid] = (2.0f/128.0f)*(h2k[tid] - vbuf[((size_t)b*SEQ + t)*HD + tid]);
    __syncthreads();
    // ---- fused: gu2 (registers) + gh1 partial ----
    float gu2r[4], gu1r[4];
    {
      float acc[4]={0,0,0,0};
      #pragma unroll
      for (int oo=0;oo<4;oo++){
        float go = g2v[i0+oo];
        #pragma unroll
        for (int jj=0;jj<4;jj++){
          float w = fmaf(pw2L[1][jj*4+oo][tid], cAp, mw2[1][jj*4+oo]*cBp);
          acc[jj] = fmaf(go, w, acc[jj]);
        }
      }
      #pragma unroll
      for (int d=1; d<32; d<<=1){
        #pragma unroll
        for (int jj=0;jj<4;jj++) acc[jj] += __shfl_xor(acc[jj], d, 64);
      }
      #pragma unroll
      for (int jj=0;jj<4;jj++){
        float u=u2k[j0+jj]; float sg=sigm(u);
        gu2r[jj] = acc[jj]*sg*fmaf(u, 1.f-sg, 1.f);
      }
      float acc2[4]={0,0,0,0};
      #pragma unroll
      for (int jj=0;jj<4;jj++){
        float gj = gu2r[jj];
        #pragma unroll
        for (int ii=0;ii<4;ii++){
          float w = fmaf(pw1L[1][jj*4+ii][tid], cAp, mw1[1][jj*4+ii]*cBp);
          acc2[ii] = fmaf(gj, w, acc2[ii]);
        }
      }
      #pragma unroll
      for (int ii=0;ii<4;ii++) acc2[ii] += __shfl_xor(acc2[ii], 32, 64);
      if ((tid & 32)==0){
        int wv = tid>>6;
        #pragma unroll
        for (int ii=0;ii<4;ii++) redbuf[wv][i0+ii] = acc2[ii];
      }
    }
    __syncthreads();
    {
      unsigned seqB = (unsigned)(t+1);
      if (tid < HD){
        float p=0.f;
        #pragma unroll
        for (int w_=0;w_<8;w_++) p += redbuf[w_][tid];
        pubstore(0, seqB, tid, p);
        gh1[tid] = g2v[tid] + pollacc(0, seqB, tid, p);
      }
    }
    __syncthreads();                    // gh1 visible
    // ---- gu1 (registers) ----
    {
      float acc[4]={0,0,0,0};
      #pragma unroll
      for (int oo=0;oo<4;oo++){
        float go = gh1[i0+oo];
        #pragma unroll
        for (int jj=0;jj<4;jj++){
          float w = fmaf(pw2L[0][jj*4+oo][tid], cAp, mw2[0][jj*4+oo]*cBp);
          acc[jj] = fmaf(go, w, acc[jj]);
        }
      }
      #pragma unroll
      for (int d=1; d<32; d<<=1){
        #pragma unroll
        for (int jj=0;jj<4;jj++) acc[jj] += __shfl_xor(acc[jj], d, 64);
      }
      #pragma unroll
      for (int jj=0;jj<4;jj++){
        float u=u1k[j0+jj]; float sg=sigm(u);
        gu1r[jj] = acc[jj]*sg*fmaf(u, 1.f-sg, 1.f);
      }
    }
    // ---- momentum update (no sync needed: register gu's, stable LDS) ----
    {
      if (iG==0){
        #pragma unroll
        for (int jj=0;jj<4;jj++){
          int j=j0+jj;
          b1m[0][j] = fmaf(et, b1m[0][j], -th*gu1r[jj]);
          b1m[1][j] = fmaf(et, b1m[1][j], -th*gu2r[jj]);
        }
      }
      if (tid < 32){
        b2m[0][tid] = fmaf(et, b2m[0][tid], -th*gh1[wg*32+tid]);
        b2m[1][tid] = fmaf(et, b2m[1][tid], -th*g2v[wg*32+tid]);
      }
      #pragma unroll
      for (int jj=0;jj<4;jj++){
        float s1j = s1k[j0+jj], s2j = s2k[j0+jj];
        #pragma unroll
        for (int ii=0;ii<4;ii++){
          int e = jj*4+ii;
          mw1[0][e] = fmaf(et, mw1[0][e], -th*(kvecB[cur][i0+ii]*gu1r[jj]));
          mw1[1][e] = fmaf(et, mw1[1][e], -th*(h1k[i0+ii]*gu2r[jj]));
          mw2[0][e] = fmaf(et, mw2[0][e], -th*(s1j*gh1[i0+ii]));
          mw2[1][e] = fmaf(et, mw2[1][e], -th*(s2j*g2v[i0+ii]));
        }
      }
    }
    // ---- prefetch q_t / k_{t+1} into the other parity buffer (no WAR) ----
    if (tid < HD){
      qvecB[cur^1][tid] = qbuf[((size_t)b*SEQ + t)*HD + tid];
      int tn = (t < SEQ-1) ? t+1 : SEQ-1;
      kvecB[cur^1][tid] = kbuf[((size_t)b*SEQ + tn)*HD + tid];
    }
    __syncthreads();                    // new k/q + b2m visible
    fwdDual(t, true, (unsigned)(t+2), cur^1, 1.f - al, 1.f);
    cAp = 1.f - al; cBp = 1.f;
  }
}

extern "C" void kernel_launch(void* const* d_in, const int* in_sizes, int n_in,
                              void* d_out, int out_size, void* d_ws, size_t ws_size,
                              hipStream_t stream)
{
  (void)in_sizes; (void)n_in; (void)out_size; (void)ws_size;
  const float* x    = (const float*)d_in[0];
  const float* Wq   = (const float*)d_in[1];
  const float* Wk   = (const float*)d_in[2];
  const float* Wv   = (const float*)d_in[3];
  const float* w_lr = (const float*)d_in[4];
  const float* b_lr = (const float*)d_in[5];
  const float* w_fg = (const float*)d_in[6];
  const float* b_fg = (const float*)d_in[7];
  const float* w_mo = (const float*)d_in[8];
  const float* b_mo = (const float*)d_in[9];
  const float* w1_0 = (const float*)d_in[10];
  const float* b1_0 = (const float*)d_in[11];
  const float* w2_0 = (const float*)d_in[12];
  const float* b2_0 = (const float*)d_in[13];
  const float* m_w1_0 = (const float*)d_in[14];
  const float* m_b1_0 = (const float*)d_in[15];
  const float* m_w2_0 = (const float*)d_in[16];
  const float* m_b2_0 = (const float*)d_in[17];
  const float* w1_1 = (const float*)d_in[18];
  const float* b1_1 = (const float*)d_in[19];
  const float* w2_1 = (const float*)d_in[20];
  const float* b2_1 = (const float*)d_in[21];
  const float* m_w1_1 = (const float*)d_in[22];
  const float* m_b1_1 = (const float*)d_in[23];
  const float* m_w2_1 = (const float*)d_in[24];
  const float* m_b2_1 = (const float*)d_in[25];

  float* wsf = (float*)d_ws;
  // 64-bit tagged exchange slots: 4 batches x 3 types x 4 WGs x 256 words
  unsigned long long* red = (unsigned long long*)d_ws;   // 98304 B
  float* qbuf = wsf + 32768;
  float* kbuf = qbuf + NB*SEQ*HD;
  float* vbuf = kbuf + NB*SEQ*HD;
  float* thb  = vbuf + NB*SEQ*HD;
  float* alb  = thb + NB*SEQ;
  float* etb  = alb + NB*SEQ;
  // No memset needed: ws is re-poisoned to 0xAA before every launch;
  // 0xAAAAAAAA never equals a valid seq tag (tags are 1..258).

  qkv_kernel<<<dim3(NB*SEQ), dim3(HD), 0, stream>>>(
      x, Wq, Wk, Wv, w_lr, b_lr, w_fg, b_fg, w_mo, b_mo,
      qbuf, kbuf, vbuf, thb, alb, etb);

  scan_kernel<<<dim3(NB*NWG), dim3(512), 0, stream>>>(
      w1_0, b1_0, w2_0, b2_0, m_w1_0, m_b1_0, m_w2_0, m_b2_0,
      w1_1, b1_1, w2_1, b2_1, m_w1_1, m_b1_1, m_w2_1, m_b2_1,
      qbuf, kbuf, vbuf, thb, alb, etb,
      red, (float*)d_out);
}

// Round 7
// 2595.812 us; speedup vs baseline: 1.4919x; 1.2726x over previous
//
#include <hip/hip_runtime.h>

// NeuralMemory scan: B=4, S=256, H=128, EXP=2, DEPTH=2.
// p_t = p0*(1-a_t) + m_t. m in registers; p0 in LDS [plane][tid].
// Round 6 (resubmit; round 6 bench was lost to GPUAcquisitionTimeout):
// shorten the serial chain. Post-butterfly values live in REGISTERS across
// stages and across the t-loop (u1/s1/u2/s2 etc) -- their consumers are
// always the same jG group. g2v LDS stage removed (per-thread regs from
// h2k + prefetched v). Layer-1 momentum updates overlapped with the
// B-exchange round trip. 7 syncthreads/step (was 10).

constexpr int HD  = 128;   // H
constexpr int SEQ = 256;   // S
constexpr int NB  = 4;     // B
constexpr int ED  = 256;   // H*EXP
constexpr int CW  = 64;    // hidden units per WG per layer (ED/NWG)
constexpr int NWG = 4;     // workgroups per batch

__device__ __forceinline__ float sigm(float x){ return 1.0f/(1.0f+__expf(-x)); }

// ---------------- kernel 1: q/k/v + gate scalars ----------------
__global__ __launch_bounds__(128) void qkv_kernel(
    const float* __restrict__ x,
    const float* __restrict__ Wq, const float* __restrict__ Wk, const float* __restrict__ Wv,
    const float* __restrict__ w_lr, const float* __restrict__ b_lr,
    const float* __restrict__ w_fg, const float* __restrict__ b_fg,
    const float* __restrict__ w_mo, const float* __restrict__ b_mo,
    float* __restrict__ qb, float* __restrict__ kb, float* __restrict__ vb,
    float* __restrict__ thb, float* __restrict__ alb, float* __restrict__ etb)
{
  const int bs = blockIdx.x;          // b*SEQ + s
  const int o  = threadIdx.x;         // 0..127
  __shared__ float xl[HD];
  __shared__ float rb[HD];
  xl[o] = x[(size_t)bs*HD + o];
  __syncthreads();

  float aq=0.f, ak=0.f, av=0.f;
  #pragma unroll 8
  for (int i=0;i<HD;i++){
    float xi = xl[i];
    aq = fmaf(xi, Wq[i*HD+o], aq);
    ak = fmaf(xi, Wk[i*HD+o], ak);
    av = fmaf(xi, Wv[i*HD+o], av);
  }
  float sq_ = aq*sigm(aq);
  float sk_ = ak*sigm(ak);
  float sv_ = av*sigm(av);

  auto bsum = [&](float v)->float {
    rb[o] = v; __syncthreads();
    for (int st=64; st>0; st>>=1){
      if (o < st) rb[o] += rb[o+st];
      __syncthreads();
    }
    float r = rb[0];
    __syncthreads();
    return r;
  };

  float nq = bsum(sq_*sq_);
  float nk = bsum(sk_*sk_);
  float dl = bsum(xl[o]*w_lr[o]);
  float df = bsum(xl[o]*w_fg[o]);
  float dm = bsum(xl[o]*w_mo[o]);

  qb[(size_t)bs*HD+o] = sq_ / fmaxf(sqrtf(nq), 1e-12f);
  kb[(size_t)bs*HD+o] = sk_ / fmaxf(sqrtf(nk), 1e-12f);
  vb[(size_t)bs*HD+o] = sv_;
  if (o==0){
    thb[bs] = sigm(dl + b_lr[0]) * 0.01f;   // MAX_LR
    alb[bs] = sigm(df + b_fg[0]);
    etb[bs] = sigm(dm + b_mo[0]);
  }
}

// ---------------- kernel 2: the sequential scan ----------------
__global__ __launch_bounds__(512, 1) void scan_kernel(
    const float* __restrict__ w1_0g, const float* __restrict__ b1_0g,
    const float* __restrict__ w2_0g, const float* __restrict__ b2_0g,
    const float* __restrict__ mw1_0g, const float* __restrict__ mb1_0g,
    const float* __restrict__ mw2_0g, const float* __restrict__ mb2_0g,
    const float* __restrict__ w1_1g, const float* __restrict__ b1_1g,
    const float* __restrict__ w2_1g, const float* __restrict__ b2_1g,
    const float* __restrict__ mw1_1g, const float* __restrict__ mb1_1g,
    const float* __restrict__ mw2_1g, const float* __restrict__ mb2_1g,
    const float* __restrict__ qbuf, const float* __restrict__ kbuf, const float* __restrict__ vbuf,
    const float* __restrict__ thb, const float* __restrict__ alb, const float* __restrict__ etb,
    unsigned long long* __restrict__ red, float* __restrict__ out)
{
  const int bid = blockIdx.x;
  const int b   = bid & 3;     // batch
  const int wg  = bid >> 2;    // 0..3 within batch
  const int tid = threadIdx.x;
  const int iG  = tid & 31;    // i-group (w1) / o-group (w2)
  const int jG  = tid >> 5;    // j-group 0..15
  const int i0  = iG*4;
  const int j0  = jG*4;
  const int c0  = wg*CW;

  __shared__ float pw1L[2][16][512];   // 64 KB p0 (w1), [plane][tid]
  __shared__ float pw2L[2][16][512];   // 64 KB p0 (w2)
  __shared__ float kvecB[2][HD], qvecB[2][HD];
  __shared__ float h1k[HD], h1q[HD], h2k[HD], gh1[HD];
  __shared__ float redbuf[8][256];
  __shared__ float b1p[2][CW], b1m[2][CW], b2p[2][32], b2m[2][32];

  float mw1[2][16], mw2[2][16];
  {
    const float* w1s[2]  = {w1_0g,  w1_1g};
    const float* mw1s[2] = {mw1_0g, mw1_1g};
    const float* w2s[2]  = {w2_0g,  w2_1g};
    const float* mw2s[2] = {mw2_0g, mw2_1g};
    #pragma unroll
    for (int l=0;l<2;l++){
      #pragma unroll
      for (int jj=0;jj<4;jj++){
        #pragma unroll
        for (int ii=0;ii<4;ii++){
          int gi1 = (i0+ii)*ED + (c0+j0+jj);
          pw1L[l][jj*4+ii][tid] = w1s[l][gi1];
          mw1[l][jj*4+ii] = mw1s[l][gi1];
          int gi2 = (c0+j0+jj)*HD + (i0+ii);
          pw2L[l][jj*4+ii][tid] = w2s[l][gi2];
          mw2[l][jj*4+ii] = mw2s[l][gi2];
        }
      }
    }
  }
  if (tid < CW){
    b1p[0][tid] = b1_0g[c0+tid]; b1m[0][tid] = mb1_0g[c0+tid];
    b1p[1][tid] = b1_1g[c0+tid]; b1m[1][tid] = mb1_1g[c0+tid];
  } else if (tid < CW+32){
    int oo = tid - CW;
    b2p[0][oo] = b2_0g[wg*32+oo]; b2m[0][oo] = mb2_0g[wg*32+oo];
    b2p[1][oo] = b2_1g[wg*32+oo]; b2m[1][oo] = mb2_1g[wg*32+oo];
  }

  auto pubstore = [&](int type, unsigned seq, int idx, float val){
    unsigned long long* p = red + (((b*3+type)*NWG + wg)*256 + idx);
    unsigned long long pk = ((unsigned long long)seq << 32) |
                            (unsigned long long)__float_as_uint(val);
    __hip_atomic_store(p, pk, __ATOMIC_RELAXED, __HIP_MEMORY_SCOPE_AGENT);
  };
  auto pollacc = [&](int type, unsigned seq, int idx, float own)->float{
    unsigned long long* base = red + ((b*3+type)*NWG)*256;
    const int wA=((wg+1)&3)*256+idx, wB=((wg+2)&3)*256+idx, wC=((wg+3)&3)*256+idx;
    unsigned long long vA = __hip_atomic_load(base+wA, __ATOMIC_RELAXED, __HIP_MEMORY_SCOPE_AGENT);
    unsigned long long vB = __hip_atomic_load(base+wB, __ATOMIC_RELAXED, __HIP_MEMORY_SCOPE_AGENT);
    unsigned long long vC = __hip_atomic_load(base+wC, __ATOMIC_RELAXED, __HIP_MEMORY_SCOPE_AGENT);
    float s = own; unsigned got = 0;
    while (got != 7u){
      if (!(got&1u)){
        if ((unsigned)(vA>>32)==seq){ s += __uint_as_float((unsigned)vA); got|=1u; }
        else vA = __hip_atomic_load(base+wA, __ATOMIC_RELAXED, __HIP_MEMORY_SCOPE_AGENT);
      }
      if (!(got&2u)){
        if ((unsigned)(vB>>32)==seq){ s += __uint_as_float((unsigned)vB); got|=2u; }
        else vB = __hip_atomic_load(base+wB, __ATOMIC_RELAXED, __HIP_MEMORY_SCOPE_AGENT);
      }
      if (!(got&4u)){
        if ((unsigned)(vC>>32)==seq){ s += __uint_as_float((unsigned)vC); got|=4u; }
        else vC = __hip_atomic_load(base+wC, __ATOMIC_RELAXED, __HIP_MEMORY_SCOPE_AGENT);
      }
    }
    return s;
  };

  // loop-carried per-thread state (k-path activations, own jG / i0-range)
  float u1_r[4], s1_r[4], u2_r[4], s2_r[4], h1k_r[4], v_r[4], vc_r = 0.f;

  // merged forward of q_t (output) and k_{t+1}; bi = parity of k/q buffers.
  auto fwdDual = [&](int t, bool writeOut, unsigned seq, int bi, float cA, float cB){
    // ---- layer0 u ----
    float aq[4]={0,0,0,0}, ak[4]={0,0,0,0};
    #pragma unroll
    for (int ii=0;ii<4;ii++){
      float qi = qvecB[bi][i0+ii], ki = kvecB[bi][i0+ii];
      #pragma unroll
      for (int jj=0;jj<4;jj++){
        float w = fmaf(pw1L[0][jj*4+ii][tid], cA, mw1[0][jj*4+ii]*cB);
        aq[jj] = fmaf(qi, w, aq[jj]);
        ak[jj] = fmaf(ki, w, ak[jj]);
      }
    }
    #pragma unroll
    for (int d=1; d<32; d<<=1){
      #pragma unroll
      for (int jj=0;jj<4;jj++){
        aq[jj] += __shfl_xor(aq[jj], d, 64);
        ak[jj] += __shfl_xor(ak[jj], d, 64);
      }
    }
    float sq1q[4];
    #pragma unroll
    for (int jj=0;jj<4;jj++){
      float bb = fmaf(b1p[0][j0+jj], cA, b1m[0][j0+jj]*cB);
      float uq = aq[jj]+bb, uk = ak[jj]+bb;
      u1_r[jj]=uk; s1_r[jj]=uk*sigm(uk); sq1q[jj]=uq*sigm(uq);
    }
    // ---- layer0 out partials ----
    float oq[4]={0,0,0,0}, ok[4]={0,0,0,0};
    #pragma unroll
    for (int jj=0;jj<4;jj++){
      #pragma unroll
      for (int oo=0;oo<4;oo++){
        float w = fmaf(pw2L[0][jj*4+oo][tid], cA, mw2[0][jj*4+oo]*cB);
        oq[oo] = fmaf(sq1q[jj], w, oq[oo]);
        ok[oo] = fmaf(s1_r[jj], w, ok[oo]);
      }
    }
    #pragma unroll
    for (int oo=0;oo<4;oo++){
      oq[oo] += __shfl_xor(oq[oo], 32, 64);
      ok[oo] += __shfl_xor(ok[oo], 32, 64);
    }
    if (!(tid & 32)){
      int wv = tid>>6;
      #pragma unroll
      for (int oo=0;oo<4;oo++){
        redbuf[wv][i0+oo]     = oq[oo];
        redbuf[wv][128+i0+oo] = ok[oo];
      }
    }
    __syncthreads();
    if (tid < 256){
      float p=0.f;
      #pragma unroll
      for (int w_=0; w_<8; w_++) p += redbuf[w_][tid];
      int o = tid & 127;
      if (o >= wg*32 && o < wg*32+32)
        p += fmaf(b2p[0][o-wg*32], cA, b2m[0][o-wg*32]*cB);
      pubstore(1, seq, tid, p);
      float s0 = ((tid<128) ? qvecB[bi][o] : kvecB[bi][o]) + pollacc(1, seq, tid, p);
      if (tid<128) h1q[o]=s0; else h1k[o]=s0;
    }
    __syncthreads();
    // ---- layer1 u ----
    float aq2[4]={0,0,0,0}, ak2[4]={0,0,0,0};
    #pragma unroll
    for (int ii=0;ii<4;ii++){
      float qi = h1q[i0+ii], ki = h1k[i0+ii];
      h1k_r[ii] = ki;
      #pragma unroll
      for (int jj=0;jj<4;jj++){
        float w = fmaf(pw1L[1][jj*4+ii][tid], cA, mw1[1][jj*4+ii]*cB);
        aq2[jj] = fmaf(qi, w, aq2[jj]);
        ak2[jj] = fmaf(ki, w, ak2[jj]);
      }
    }
    #pragma unroll
    for (int d=1; d<32; d<<=1){
      #pragma unroll
      for (int jj=0;jj<4;jj++){
        aq2[jj] += __shfl_xor(aq2[jj], d, 64);
        ak2[jj] += __shfl_xor(ak2[jj], d, 64);
      }
    }
    float sq2q[4];
    #pragma unroll
    for (int jj=0;jj<4;jj++){
      float bb = fmaf(b1p[1][j0+jj], cA, b1m[1][j0+jj]*cB);
      float uq = aq2[jj]+bb, uk = ak2[jj]+bb;
      u2_r[jj]=uk; s2_r[jj]=uk*sigm(uk); sq2q[jj]=uq*sigm(uq);
    }
    // ---- layer1 out partials ----
    #pragma unroll
    for (int oo=0;oo<4;oo++){ oq[oo]=0.f; ok[oo]=0.f; }
    #pragma unroll
    for (int jj=0;jj<4;jj++){
      #pragma unroll
      for (int oo=0;oo<4;oo++){
        float w = fmaf(pw2L[1][jj*4+oo][tid], cA, mw2[1][jj*4+oo]*cB);
        oq[oo] = fmaf(sq2q[jj], w, oq[oo]);
        ok[oo] = fmaf(s2_r[jj], w, ok[oo]);
      }
    }
    #pragma unroll
    for (int oo=0;oo<4;oo++){
      oq[oo] += __shfl_xor(oq[oo], 32, 64);
      ok[oo] += __shfl_xor(ok[oo], 32, 64);
    }
    if (!(tid & 32)){
      int wv = tid>>6;
      #pragma unroll
      for (int oo=0;oo<4;oo++){
        redbuf[wv][i0+oo]     = oq[oo];
        redbuf[wv][128+i0+oo] = ok[oo];
      }
    }
    __syncthreads();
    if (tid < 256){
      float p=0.f;
      #pragma unroll
      for (int w_=0; w_<8; w_++) p += redbuf[w_][tid];
      int o = tid & 127;
      if (o >= wg*32 && o < wg*32+32)
        p += fmaf(b2p[1][o-wg*32], cA, b2m[1][o-wg*32]*cB);
      pubstore(2, seq, tid, p);
      float s0 = ((tid<128) ? h1q[o] : h1k[o]) + pollacc(2, seq, tid, p);
      if (tid<128){
        if (writeOut && o >= wg*32 && o < wg*32+32)
          out[((size_t)(b*SEQ + t))*HD + o] = s0;
      } else {
        h2k[o] = s0;
      }
    }
  };

  // ---- prologue: forward k_0 with cp = p0 (cA=1, cB=0) ----
  if (tid < HD){
    kvecB[0][tid] = kbuf[((size_t)b*SEQ + 0)*HD + tid];
    qvecB[0][tid] = 0.f;
    vc_r = vbuf[((size_t)b*SEQ + 0)*HD + tid];
  }
  #pragma unroll
  for (int ii=0;ii<4;ii++) v_r[ii] = vbuf[((size_t)b*SEQ + 0)*HD + i0+ii];
  __syncthreads();
  fwdDual(0, false, 1u, 0, 1.f, 0.f);

  float cAp = 1.f, cBp = 0.f;   // coefs of p_{t-1}
  for (int t=0; t<SEQ; ++t){
    const int cur = t & 1;
    const float th = thb[b*SEQ+t];
    const float al = alb[b*SEQ+t];
    const float et = etb[b*SEQ+t];
    __syncthreads();                       // #1: h2k from prev fwd visible
    // ---- g2v in registers ----
    float g2v_r[4];
    #pragma unroll
    for (int ii=0;ii<4;ii++) g2v_r[ii] = 0.015625f*(h2k[i0+ii] - v_r[ii]);
    // ---- gu2 ----
    float acc[4]={0,0,0,0};
    #pragma unroll
    for (int oo=0;oo<4;oo++){
      float go = g2v_r[oo];
      #pragma unroll
      for (int jj=0;jj<4;jj++){
        float w = fmaf(pw2L[1][jj*4+oo][tid], cAp, mw2[1][jj*4+oo]*cBp);
        acc[jj] = fmaf(go, w, acc[jj]);
      }
    }
    #pragma unroll
    for (int d=1; d<32; d<<=1){
      #pragma unroll
      for (int jj=0;jj<4;jj++) acc[jj] += __shfl_xor(acc[jj], d, 64);
    }
    float gu2r[4];
    #pragma unroll
    for (int jj=0;jj<4;jj++){
      float u=u2_r[jj]; float sg=sigm(u);
      gu2r[jj] = acc[jj]*sg*fmaf(u, 1.f-sg, 1.f);
    }
    // ---- gh1 partial ----
    float a2[4]={0,0,0,0};
    #pragma unroll
    for (int jj=0;jj<4;jj++){
      float gj = gu2r[jj];
      #pragma unroll
      for (int ii=0;ii<4;ii++){
        float w = fmaf(pw1L[1][jj*4+ii][tid], cAp, mw1[1][jj*4+ii]*cBp);
        a2[ii] = fmaf(gj, w, a2[ii]);
      }
    }
    #pragma unroll
    for (int ii=0;ii<4;ii++) a2[ii] += __shfl_xor(a2[ii], 32, 64);
    if (!(tid & 32)){
      int wv = tid>>6;
      #pragma unroll
      for (int ii=0;ii<4;ii++) redbuf[wv][i0+ii] = a2[ii];
    }
    __syncthreads();                       // #2
    const unsigned seqB = (unsigned)(t+1);
    float pB = 0.f, g2vc = 0.f;
    if (tid < HD){
      #pragma unroll
      for (int w_=0;w_<8;w_++) pB += redbuf[w_][tid];
      pubstore(0, seqB, tid, pB);          // publish ASAP
      g2vc = 0.015625f*(h2k[tid] - vc_r);
    }
    // ---- layer-1 momentum updates: OVERLAP the B round-trip ----
    #pragma unroll
    for (int jj=0;jj<4;jj++){
      float g2j = gu2r[jj], s2j = s2_r[jj];
      #pragma unroll
      for (int ii=0;ii<4;ii++){
        int e = jj*4+ii;
        mw1[1][e] = fmaf(et, mw1[1][e], -th*(h1k_r[ii]*g2j));
        mw2[1][e] = fmaf(et, mw2[1][e], -th*(s2j*g2v_r[ii]));
      }
    }
    if (iG==0){
      #pragma unroll
      for (int jj=0;jj<4;jj++)
        b1m[1][j0+jj] = fmaf(et, b1m[1][j0+jj], -th*gu2r[jj]);
    }
    if (jG==0 && iG>=wg*8 && iG<wg*8+8){
      #pragma unroll
      for (int ii=0;ii<4;ii++)
        b2m[1][i0+ii-wg*32] = fmaf(et, b2m[1][i0+ii-wg*32], -th*g2v_r[ii]);
    }
    if (tid < HD)
      gh1[tid] = g2vc + pollacc(0, seqB, tid, pB);
    __syncthreads();                       // #3: gh1 visible
    // ---- gu1 ----
    float gh1_r[4];
    #pragma unroll
    for (int ii=0;ii<4;ii++) gh1_r[ii] = gh1[i0+ii];
    #pragma unroll
    for (int jj=0;jj<4;jj++) acc[jj]=0.f;
    #pragma unroll
    for (int oo=0;oo<4;oo++){
      float go = gh1_r[oo];
      #pragma unroll
      for (int jj=0;jj<4;jj++){
        float w = fmaf(pw2L[0][jj*4+oo][tid], cAp, mw2[0][jj*4+oo]*cBp);
        acc[jj] = fmaf(go, w, acc[jj]);
      }
    }
    #pragma unroll
    for (int d=1; d<32; d<<=1){
      #pragma unroll
      for (int jj=0;jj<4;jj++) acc[jj] += __shfl_xor(acc[jj], d, 64);
    }
    float gu1r[4];
    #pragma unroll
    for (int jj=0;jj<4;jj++){
      float u=u1_r[jj]; float sg=sigm(u);
      gu1r[jj] = acc[jj]*sg*fmaf(u, 1.f-sg, 1.f);
    }
    // ---- layer-0 momentum updates ----
    float kv_r[4];
    #pragma unroll
    for (int ii=0;ii<4;ii++) kv_r[ii] = kvecB[cur][i0+ii];
    #pragma unroll
    for (int jj=0;jj<4;jj++){
      float g1j = gu1r[jj], s1j = s1_r[jj];
      #pragma unroll
      for (int ii=0;ii<4;ii++){
        int e = jj*4+ii;
        mw1[0][e] = fmaf(et, mw1[0][e], -th*(kv_r[ii]*g1j));
        mw2[0][e] = fmaf(et, mw2[0][e], -th*(s1j*gh1_r[ii]));
      }
    }
    if (iG==0){
      #pragma unroll
      for (int jj=0;jj<4;jj++)
        b1m[0][j0+jj] = fmaf(et, b1m[0][j0+jj], -th*gu1r[jj]);
    }
    if (jG==0 && iG>=wg*8 && iG<wg*8+8){
      #pragma unroll
      for (int ii=0;ii<4;ii++)
        b2m[0][i0+ii-wg*32] = fmaf(et, b2m[0][i0+ii-wg*32], -th*gh1_r[ii]);
    }
    // ---- prefetch next q/k (LDS parity) and v (registers) ----
    {
      int tn = (t < SEQ-1) ? t+1 : SEQ-1;
      if (tid < HD){
        qvecB[cur^1][tid] = qbuf[((size_t)b*SEQ + t)*HD + tid];
        kvecB[cur^1][tid] = kbuf[((size_t)b*SEQ + tn)*HD + tid];
        vc_r = vbuf[((size_t)b*SEQ + tn)*HD + tid];
      }
      #pragma unroll
      for (int ii=0;ii<4;ii++)
        v_r[ii] = vbuf[((size_t)b*SEQ + tn)*HD + i0+ii];
    }
    const float cA = 1.f - al;
    __syncthreads();                       // #4: m/bias updates + new k/q
    fwdDual(t, true, (unsigned)(t+2), cur^1, cA, 1.f);
    cAp = cA; cBp = 1.f;
  }
}

extern "C" void kernel_launch(void* const* d_in, const int* in_sizes, int n_in,
                              void* d_out, int out_size, void* d_ws, size_t ws_size,
                              hipStream_t stream)
{
  (void)in_sizes; (void)n_in; (void)out_size; (void)ws_size;
  const float* x    = (const float*)d_in[0];
  const float* Wq   = (const float*)d_in[1];
  const float* Wk   = (const float*)d_in[2];
  const float* Wv   = (const float*)d_in[3];
  const float* w_lr = (const float*)d_in[4];
  const float* b_lr = (const float*)d_in[5];
  const float* w_fg = (const float*)d_in[6];
  const float* b_fg = (const float*)d_in[7];
  const float* w_mo = (const float*)d_in[8];
  const float* b_mo = (const float*)d_in[9];
  const float* w1_0 = (const float*)d_in[10];
  const float* b1_0 = (const float*)d_in[11];
  const float* w2_0 = (const float*)d_in[12];
  const float* b2_0 = (const float*)d_in[13];
  const float* m_w1_0 = (const float*)d_in[14];
  const float* m_b1_0 = (const float*)d_in[15];
  const float* m_w2_0 = (const float*)d_in[16];
  const float* m_b2_0 = (const float*)d_in[17];
  const float* w1_1 = (const float*)d_in[18];
  const float* b1_1 = (const float*)d_in[19];
  const float* w2_1 = (const float*)d_in[20];
  const float* b2_1 = (const float*)d_in[21];
  const float* m_w1_1 = (const float*)d_in[22];
  const float* m_b1_1 = (const float*)d_in[23];
  const float* m_w2_1 = (const float*)d_in[24];
  const float* m_b2_1 = (const float*)d_in[25];

  float* wsf = (float*)d_ws;
  unsigned long long* red = (unsigned long long*)d_ws;   // 98304 B of slots
  float* qbuf = wsf + 32768;
  float* kbuf = qbuf + NB*SEQ*HD;
  float* vbuf = kbuf + NB*SEQ*HD;
  float* thb  = vbuf + NB*SEQ*HD;
  float* alb  = thb + NB*SEQ;
  float* etb  = alb + NB*SEQ;
  // ws re-poisoned to 0xAA each launch; 0xAAAAAAAA is never a valid seq tag.

  qkv_kernel<<<dim3(NB*SEQ), dim3(HD), 0, stream>>>(
      x, Wq, Wk, Wv, w_lr, b_lr, w_fg, b_fg, w_mo, b_mo,
      qbuf, kbuf, vbuf, thb, alb, etb);

  scan_kernel<<<dim3(NB*NWG), dim3(512), 0, stream>>>(
      w1_0, b1_0, w2_0, b2_0, m_w1_0, m_b1_0, m_w2_0, m_b2_0,
      w1_1, b1_1, w2_1, b2_1, m_w1_1, m_b1_1, m_w2_1, m_b2_1,
      qbuf, kbuf, vbuf, thb, alb, etb,
      red, (float*)d_out);
}

// Round 8
// 2434.047 us; speedup vs baseline: 1.5910x; 1.0665x over previous
//
#include <hip/hip_runtime.h>

// NeuralMemory scan: B=4, S=256, H=128, EXP=2, DEPTH=2.
// Round 8: n-formulation. Carry ACTUAL weights n_t = p0*(1-a_t) + m_t in
// registers (not momentum): n_t = eta*n_{t-1} + c_t*p0 - theta*g, with
// c_t = (1-a_t) - eta*(1-a_{t-1}). All 7 matvec stages now use register
// weights directly (no fmaf(p0,cA,m*cB) reconstruct, no per-stage LDS read);
// p0 (LDS [plane][tid]) is read only in the update stage. Biases likewise.
// Cross-WG exchange: 64-bit tagged words, relaxed agent-scope atomics.

constexpr int HD  = 128;   // H
constexpr int SEQ = 256;   // S
constexpr int NB  = 4;     // B
constexpr int ED  = 256;   // H*EXP
constexpr int CW  = 64;    // hidden units per WG per layer (ED/NWG)
constexpr int NWG = 4;     // workgroups per batch

__device__ __forceinline__ float sigm(float x){ return 1.0f/(1.0f+__expf(-x)); }

// ---------------- kernel 1: q/k/v + gate scalars ----------------
__global__ __launch_bounds__(128) void qkv_kernel(
    const float* __restrict__ x,
    const float* __restrict__ Wq, const float* __restrict__ Wk, const float* __restrict__ Wv,
    const float* __restrict__ w_lr, const float* __restrict__ b_lr,
    const float* __restrict__ w_fg, const float* __restrict__ b_fg,
    const float* __restrict__ w_mo, const float* __restrict__ b_mo,
    float* __restrict__ qb, float* __restrict__ kb, float* __restrict__ vb,
    float* __restrict__ thb, float* __restrict__ alb, float* __restrict__ etb)
{
  const int bs = blockIdx.x;          // b*SEQ + s
  const int o  = threadIdx.x;         // 0..127
  __shared__ float xl[HD];
  __shared__ float rb[HD];
  xl[o] = x[(size_t)bs*HD + o];
  __syncthreads();

  float aq=0.f, ak=0.f, av=0.f;
  #pragma unroll 8
  for (int i=0;i<HD;i++){
    float xi = xl[i];
    aq = fmaf(xi, Wq[i*HD+o], aq);
    ak = fmaf(xi, Wk[i*HD+o], ak);
    av = fmaf(xi, Wv[i*HD+o], av);
  }
  float sq_ = aq*sigm(aq);
  float sk_ = ak*sigm(ak);
  float sv_ = av*sigm(av);

  auto bsum = [&](float v)->float {
    rb[o] = v; __syncthreads();
    for (int st=64; st>0; st>>=1){
      if (o < st) rb[o] += rb[o+st];
      __syncthreads();
    }
    float r = rb[0];
    __syncthreads();
    return r;
  };

  float nq = bsum(sq_*sq_);
  float nk = bsum(sk_*sk_);
  float dl = bsum(xl[o]*w_lr[o]);
  float df = bsum(xl[o]*w_fg[o]);
  float dm = bsum(xl[o]*w_mo[o]);

  qb[(size_t)bs*HD+o] = sq_ / fmaxf(sqrtf(nq), 1e-12f);
  kb[(size_t)bs*HD+o] = sk_ / fmaxf(sqrtf(nk), 1e-12f);
  vb[(size_t)bs*HD+o] = sv_;
  if (o==0){
    thb[bs] = sigm(dl + b_lr[0]) * 0.01f;   // MAX_LR
    alb[bs] = sigm(df + b_fg[0]);
    etb[bs] = sigm(dm + b_mo[0]);
  }
}

// ---------------- kernel 2: the sequential scan ----------------
__global__ __launch_bounds__(512, 1) void scan_kernel(
    const float* __restrict__ w1_0g, const float* __restrict__ b1_0g,
    const float* __restrict__ w2_0g, const float* __restrict__ b2_0g,
    const float* __restrict__ mw1_0g, const float* __restrict__ mb1_0g,
    const float* __restrict__ mw2_0g, const float* __restrict__ mb2_0g,
    const float* __restrict__ w1_1g, const float* __restrict__ b1_1g,
    const float* __restrict__ w2_1g, const float* __restrict__ b2_1g,
    const float* __restrict__ mw1_1g, const float* __restrict__ mb1_1g,
    const float* __restrict__ mw2_1g, const float* __restrict__ mb2_1g,
    const float* __restrict__ qbuf, const float* __restrict__ kbuf, const float* __restrict__ vbuf,
    const float* __restrict__ thb, const float* __restrict__ alb, const float* __restrict__ etb,
    unsigned long long* __restrict__ red, float* __restrict__ out)
{
  const int bid = blockIdx.x;
  const int b   = bid & 3;     // batch
  const int wg  = bid >> 2;    // 0..3 within batch
  const int tid = threadIdx.x;
  const int iG  = tid & 31;    // i-group (w1) / o-group (w2)
  const int jG  = tid >> 5;    // j-group 0..15
  const int i0  = iG*4;
  const int j0  = jG*4;
  const int c0  = wg*CW;

  __shared__ float pw1L[2][16][512];   // 64 KB p0 (w1), [plane][tid]
  __shared__ float pw2L[2][16][512];   // 64 KB p0 (w2)
  __shared__ float kvecB[2][HD], qvecB[2][HD];
  __shared__ float h1k[HD], h1q[HD], h2k[HD], gh1[HD];
  __shared__ float redbuf[8][256];
  __shared__ float b1p[2][CW], b1n[2][CW], b2p[2][32], b2n[2][32];

  // actual weights n = p0*(1-a) + m, carried in registers
  float nw1[2][16], nw2[2][16];
  {
    const float* w1s[2]  = {w1_0g,  w1_1g};
    const float* mw1s[2] = {mw1_0g, mw1_1g};
    const float* w2s[2]  = {w2_0g,  w2_1g};
    const float* mw2s[2] = {mw2_0g, mw2_1g};
    #pragma unroll
    for (int l=0;l<2;l++){
      #pragma unroll
      for (int jj=0;jj<4;jj++){
        #pragma unroll
        for (int ii=0;ii<4;ii++){
          int gi1 = (i0+ii)*ED + (c0+j0+jj);
          float p1 = w1s[l][gi1];
          pw1L[l][jj*4+ii][tid] = p1;
          nw1[l][jj*4+ii] = p1 + mw1s[l][gi1];   // n_{-1} = p0 + m0
          int gi2 = (c0+j0+jj)*HD + (i0+ii);
          float p2 = w2s[l][gi2];
          pw2L[l][jj*4+ii][tid] = p2;
          nw2[l][jj*4+ii] = p2 + mw2s[l][gi2];
        }
      }
    }
  }
  if (tid < CW){
    float p0a = b1_0g[c0+tid], p1a = b1_1g[c0+tid];
    b1p[0][tid] = p0a; b1n[0][tid] = p0a + mb1_0g[c0+tid];
    b1p[1][tid] = p1a; b1n[1][tid] = p1a + mb1_1g[c0+tid];
  } else if (tid < CW+32){
    int oo = tid - CW;
    float p0a = b2_0g[wg*32+oo], p1a = b2_1g[wg*32+oo];
    b2p[0][oo] = p0a; b2n[0][oo] = p0a + mb2_0g[wg*32+oo];
    b2p[1][oo] = p1a; b2n[1][oo] = p1a + mb2_1g[wg*32+oo];
  }

  auto pubstore = [&](int type, unsigned seq, int idx, float val){
    unsigned long long* p = red + (((b*3+type)*NWG + wg)*256 + idx);
    unsigned long long pk = ((unsigned long long)seq << 32) |
                            (unsigned long long)__float_as_uint(val);
    __hip_atomic_store(p, pk, __ATOMIC_RELAXED, __HIP_MEMORY_SCOPE_AGENT);
  };
  auto pollacc = [&](int type, unsigned seq, int idx, float own)->float{
    unsigned long long* base = red + ((b*3+type)*NWG)*256;
    const int wA=((wg+1)&3)*256+idx, wB=((wg+2)&3)*256+idx, wC=((wg+3)&3)*256+idx;
    unsigned long long vA = __hip_atomic_load(base+wA, __ATOMIC_RELAXED, __HIP_MEMORY_SCOPE_AGENT);
    unsigned long long vB = __hip_atomic_load(base+wB, __ATOMIC_RELAXED, __HIP_MEMORY_SCOPE_AGENT);
    unsigned long long vC = __hip_atomic_load(base+wC, __ATOMIC_RELAXED, __HIP_MEMORY_SCOPE_AGENT);
    float s = own; unsigned got = 0;
    while (got != 7u){
      if (!(got&1u)){
        if ((unsigned)(vA>>32)==seq){ s += __uint_as_float((unsigned)vA); got|=1u; }
        else vA = __hip_atomic_load(base+wA, __ATOMIC_RELAXED, __HIP_MEMORY_SCOPE_AGENT);
      }
      if (!(got&2u)){
        if ((unsigned)(vB>>32)==seq){ s += __uint_as_float((unsigned)vB); got|=2u; }
        else vB = __hip_atomic_load(base+wB, __ATOMIC_RELAXED, __HIP_MEMORY_SCOPE_AGENT);
      }
      if (!(got&4u)){
        if ((unsigned)(vC>>32)==seq){ s += __uint_as_float((unsigned)vC); got|=4u; }
        else vC = __hip_atomic_load(base+wC, __ATOMIC_RELAXED, __HIP_MEMORY_SCOPE_AGENT);
      }
    }
    return s;
  };

  // loop-carried per-thread state (k-path activations, own jG / i0-range)
  float u1_r[4], s1_r[4], u2_r[4], s2_r[4], h1k_r[4], v_r[4], vc_r = 0.f;

  // merged forward of q_t (output) and k_{t+1}; weights = nw (current n_t).
  auto fwdDual = [&](int t, bool writeOut, unsigned seq, int bi){
    // ---- layer0 u ----
    float aq[4]={0,0,0,0}, ak[4]={0,0,0,0};
    #pragma unroll
    for (int ii=0;ii<4;ii++){
      float qi = qvecB[bi][i0+ii], ki = kvecB[bi][i0+ii];
      #pragma unroll
      for (int jj=0;jj<4;jj++){
        float w = nw1[0][jj*4+ii];
        aq[jj] = fmaf(qi, w, aq[jj]);
        ak[jj] = fmaf(ki, w, ak[jj]);
      }
    }
    #pragma unroll
    for (int d=1; d<32; d<<=1){
      #pragma unroll
      for (int jj=0;jj<4;jj++){
        aq[jj] += __shfl_xor(aq[jj], d, 64);
        ak[jj] += __shfl_xor(ak[jj], d, 64);
      }
    }
    float sq1q[4];
    #pragma unroll
    for (int jj=0;jj<4;jj++){
      float bb = b1n[0][j0+jj];
      float uq = aq[jj]+bb, uk = ak[jj]+bb;
      u1_r[jj]=uk; s1_r[jj]=uk*sigm(uk); sq1q[jj]=uq*sigm(uq);
    }
    // ---- layer0 out partials ----
    float oq[4]={0,0,0,0}, ok[4]={0,0,0,0};
    #pragma unroll
    for (int jj=0;jj<4;jj++){
      #pragma unroll
      for (int oo=0;oo<4;oo++){
        float w = nw2[0][jj*4+oo];
        oq[oo] = fmaf(sq1q[jj], w, oq[oo]);
        ok[oo] = fmaf(s1_r[jj], w, ok[oo]);
      }
    }
    #pragma unroll
    for (int oo=0;oo<4;oo++){
      oq[oo] += __shfl_xor(oq[oo], 32, 64);
      ok[oo] += __shfl_xor(ok[oo], 32, 64);
    }
    if (!(tid & 32)){
      int wv = tid>>6;
      #pragma unroll
      for (int oo=0;oo<4;oo++){
        redbuf[wv][i0+oo]     = oq[oo];
        redbuf[wv][128+i0+oo] = ok[oo];
      }
    }
    __syncthreads();
    if (tid < 256){
      float p=0.f;
      #pragma unroll
      for (int w_=0; w_<8; w_++) p += redbuf[w_][tid];
      int o = tid & 127;
      if (o >= wg*32 && o < wg*32+32)
        p += b2n[0][o-wg*32];
      pubstore(1, seq, tid, p);
      float s0 = ((tid<128) ? qvecB[bi][o] : kvecB[bi][o]) + pollacc(1, seq, tid, p);
      if (tid<128) h1q[o]=s0; else h1k[o]=s0;
    }
    __syncthreads();
    // ---- layer1 u ----
    float aq2[4]={0,0,0,0}, ak2[4]={0,0,0,0};
    #pragma unroll
    for (int ii=0;ii<4;ii++){
      float qi = h1q[i0+ii], ki = h1k[i0+ii];
      h1k_r[ii] = ki;
      #pragma unroll
      for (int jj=0;jj<4;jj++){
        float w = nw1[1][jj*4+ii];
        aq2[jj] = fmaf(qi, w, aq2[jj]);
        ak2[jj] = fmaf(ki, w, ak2[jj]);
      }
    }
    #pragma unroll
    for (int d=1; d<32; d<<=1){
      #pragma unroll
      for (int jj=0;jj<4;jj++){
        aq2[jj] += __shfl_xor(aq2[jj], d, 64);
        ak2[jj] += __shfl_xor(ak2[jj], d, 64);
      }
    }
    float sq2q[4];
    #pragma unroll
    for (int jj=0;jj<4;jj++){
      float bb = b1n[1][j0+jj];
      float uq = aq2[jj]+bb, uk = ak2[jj]+bb;
      u2_r[jj]=uk; s2_r[jj]=uk*sigm(uk); sq2q[jj]=uq*sigm(uq);
    }
    // ---- layer1 out partials ----
    #pragma unroll
    for (int oo=0;oo<4;oo++){ oq[oo]=0.f; ok[oo]=0.f; }
    #pragma unroll
    for (int jj=0;jj<4;jj++){
      #pragma unroll
      for (int oo=0;oo<4;oo++){
        float w = nw2[1][jj*4+oo];
        oq[oo] = fmaf(sq2q[jj], w, oq[oo]);
        ok[oo] = fmaf(s2_r[jj], w, ok[oo]);
      }
    }
    #pragma unroll
    for (int oo=0;oo<4;oo++){
      oq[oo] += __shfl_xor(oq[oo], 32, 64);
      ok[oo] += __shfl_xor(ok[oo], 32, 64);
    }
    if (!(tid & 32)){
      int wv = tid>>6;
      #pragma unroll
      for (int oo=0;oo<4;oo++){
        redbuf[wv][i0+oo]     = oq[oo];
        redbuf[wv][128+i0+oo] = ok[oo];
      }
    }
    __syncthreads();
    if (tid < 256){
      float p=0.f;
      #pragma unroll
      for (int w_=0; w_<8; w_++) p += redbuf[w_][tid];
      int o = tid & 127;
      if (o >= wg*32 && o < wg*32+32)
        p += b2n[1][o-wg*32];
      pubstore(2, seq, tid, p);
      float s0 = ((tid<128) ? h1q[o] : h1k[o]) + pollacc(2, seq, tid, p);
      if (tid<128){
        if (writeOut && o >= wg*32 && o < wg*32+32)
          out[((size_t)(b*SEQ + t))*HD + o] = s0;
      } else {
        h2k[o] = s0;
      }
    }
  };

  // ---- prologue: forward k_0 with n_{-1} = p0 + m0 (m0=0 pristine) ----
  if (tid < HD){
    kvecB[0][tid] = kbuf[((size_t)b*SEQ + 0)*HD + tid];
    qvecB[0][tid] = 0.f;
    vc_r = vbuf[((size_t)b*SEQ + 0)*HD + tid];
  }
  #pragma unroll
  for (int ii=0;ii<4;ii++) v_r[ii] = vbuf[((size_t)b*SEQ + 0)*HD + i0+ii];
  __syncthreads();
  fwdDual(0, false, 1u, 0);

  float dPrev = 1.f;   // 1 - alpha_{-1}
  for (int t=0; t<SEQ; ++t){
    const int cur = t & 1;
    const float th = thb[b*SEQ+t];
    const float al = alb[b*SEQ+t];
    const float et = etb[b*SEQ+t];
    const float dcur = 1.f - al;
    const float cP = dcur - et*dPrev;      // p0 coefficient for the n-update
    __syncthreads();                       // #1: h2k from prev fwd visible
    // ---- g2v in registers ----
    float g2v_r[4];
    #pragma unroll
    for (int ii=0;ii<4;ii++) g2v_r[ii] = 0.015625f*(h2k[i0+ii] - v_r[ii]);
    // ---- gu2 (uses n_{t-1}) ----
    float acc[4]={0,0,0,0};
    #pragma unroll
    for (int oo=0;oo<4;oo++){
      float go = g2v_r[oo];
      #pragma unroll
      for (int jj=0;jj<4;jj++)
        acc[jj] = fmaf(go, nw2[1][jj*4+oo], acc[jj]);
    }
    #pragma unroll
    for (int d=1; d<32; d<<=1){
      #pragma unroll
      for (int jj=0;jj<4;jj++) acc[jj] += __shfl_xor(acc[jj], d, 64);
    }
    float gu2r[4];
    #pragma unroll
    for (int jj=0;jj<4;jj++){
      float u=u2_r[jj]; float sg=sigm(u);
      gu2r[jj] = acc[jj]*sg*fmaf(u, 1.f-sg, 1.f);
    }
    // ---- gh1 partial ----
    float a2[4]={0,0,0,0};
    #pragma unroll
    for (int jj=0;jj<4;jj++){
      float gj = gu2r[jj];
      #pragma unroll
      for (int ii=0;ii<4;ii++)
        a2[ii] = fmaf(gj, nw1[1][jj*4+ii], a2[ii]);
    }
    #pragma unroll
    for (int ii=0;ii<4;ii++) a2[ii] += __shfl_xor(a2[ii], 32, 64);
    if (!(tid & 32)){
      int wv = tid>>6;
      #pragma unroll
      for (int ii=0;ii<4;ii++) redbuf[wv][i0+ii] = a2[ii];
    }
    __syncthreads();                       // #2
    const unsigned seqB = (unsigned)(t+1);
    float pB = 0.f, g2vc = 0.f;
    if (tid < HD){
      #pragma unroll
      for (int w_=0;w_<8;w_++) pB += redbuf[w_][tid];
      pubstore(0, seqB, tid, pB);          // publish ASAP
      g2vc = 0.015625f*(h2k[tid] - vc_r);
    }
    // ---- layer-1 n-updates: OVERLAP the B round-trip ----
    #pragma unroll
    for (int jj=0;jj<4;jj++){
      float g2j = gu2r[jj], s2j = s2_r[jj];
      #pragma unroll
      for (int ii=0;ii<4;ii++){
        int e = jj*4+ii;
        nw1[1][e] = fmaf(et, nw1[1][e],
                         fmaf(cP, pw1L[1][e][tid], -th*(h1k_r[ii]*g2j)));
        nw2[1][e] = fmaf(et, nw2[1][e],
                         fmaf(cP, pw2L[1][e][tid], -th*(s2j*g2v_r[ii])));
      }
    }
    if (iG==0){
      #pragma unroll
      for (int jj=0;jj<4;jj++)
        b1n[1][j0+jj] = fmaf(et, b1n[1][j0+jj],
                             fmaf(cP, b1p[1][j0+jj], -th*gu2r[jj]));
    }
    if (jG==0 && iG>=wg*8 && iG<wg*8+8){
      #pragma unroll
      for (int ii=0;ii<4;ii++)
        b2n[1][i0+ii-wg*32] = fmaf(et, b2n[1][i0+ii-wg*32],
                                   fmaf(cP, b2p[1][i0+ii-wg*32], -th*g2v_r[ii]));
    }
    if (tid < HD)
      gh1[tid] = g2vc + pollacc(0, seqB, tid, pB);
    __syncthreads();                       // #3: gh1 visible
    // ---- gu1 (uses layer-0 n_{t-1}, not yet updated) ----
    float gh1_r[4];
    #pragma unroll
    for (int ii=0;ii<4;ii++) gh1_r[ii] = gh1[i0+ii];
    #pragma unroll
    for (int jj=0;jj<4;jj++) acc[jj]=0.f;
    #pragma unroll
    for (int oo=0;oo<4;oo++){
      float go = gh1_r[oo];
      #pragma unroll
      for (int jj=0;jj<4;jj++)
        acc[jj] = fmaf(go, nw2[0][jj*4+oo], acc[jj]);
    }
    #pragma unroll
    for (int d=1; d<32; d<<=1){
      #pragma unroll
      for (int jj=0;jj<4;jj++) acc[jj] += __shfl_xor(acc[jj], d, 64);
    }
    float gu1r[4];
    #pragma unroll
    for (int jj=0;jj<4;jj++){
      float u=u1_r[jj]; float sg=sigm(u);
      gu1r[jj] = acc[jj]*sg*fmaf(u, 1.f-sg, 1.f);
    }
    // ---- layer-0 n-updates ----
    float kv_r[4];
    #pragma unroll
    for (int ii=0;ii<4;ii++) kv_r[ii] = kvecB[cur][i0+ii];
    #pragma unroll
    for (int jj=0;jj<4;jj++){
      float g1j = gu1r[jj], s1j = s1_r[jj];
      #pragma unroll
      for (int ii=0;ii<4;ii++){
        int e = jj*4+ii;
        nw1[0][e] = fmaf(et, nw1[0][e],
                         fmaf(cP, pw1L[0][e][tid], -th*(kv_r[ii]*g1j)));
        nw2[0][e] = fmaf(et, nw2[0][e],
                         fmaf(cP, pw2L[0][e][tid], -th*(s1j*gh1_r[ii])));
      }
    }
    if (iG==0){
      #pragma unroll
      for (int jj=0;jj<4;jj++)
        b1n[0][j0+jj] = fmaf(et, b1n[0][j0+jj],
                             fmaf(cP, b1p[0][j0+jj], -th*gu1r[jj]));
    }
    if (jG==0 && iG>=wg*8 && iG<wg*8+8){
      #pragma unroll
      for (int ii=0;ii<4;ii++)
        b2n[0][i0+ii-wg*32] = fmaf(et, b2n[0][i0+ii-wg*32],
                                   fmaf(cP, b2p[0][i0+ii-wg*32], -th*gh1_r[ii]));
    }
    // ---- prefetch next q/k (LDS parity) and v (registers) ----
    {
      int tn = (t < SEQ-1) ? t+1 : SEQ-1;
      if (tid < HD){
        qvecB[cur^1][tid] = qbuf[((size_t)b*SEQ + t)*HD + tid];
        kvecB[cur^1][tid] = kbuf[((size_t)b*SEQ + tn)*HD + tid];
        vc_r = vbuf[((size_t)b*SEQ + tn)*HD + tid];
      }
      #pragma unroll
      for (int ii=0;ii<4;ii++)
        v_r[ii] = vbuf[((size_t)b*SEQ + tn)*HD + i0+ii];
    }
    dPrev = dcur;
    __syncthreads();                       // #4: n/bias updates + new k/q
    fwdDual(t, true, (unsigned)(t+2), cur^1);
  }
}

extern "C" void kernel_launch(void* const* d_in, const int* in_sizes, int n_in,
                              void* d_out, int out_size, void* d_ws, size_t ws_size,
                              hipStream_t stream)
{
  (void)in_sizes; (void)n_in; (void)out_size; (void)ws_size;
  const float* x    = (const float*)d_in[0];
  const float* Wq   = (const float*)d_in[1];
  const float* Wk   = (const float*)d_in[2];
  const float* Wv   = (const float*)d_in[3];
  const float* w_lr = (const float*)d_in[4];
  const float* b_lr = (const float*)d_in[5];
  const float* w_fg = (const float*)d_in[6];
  const float* b_fg = (const float*)d_in[7];
  const float* w_mo = (const float*)d_in[8];
  const float* b_mo = (const float*)d_in[9];
  const float* w1_0 = (const float*)d_in[10];
  const float* b1_0 = (const float*)d_in[11];
  const float* w2_0 = (const float*)d_in[12];
  const float* b2_0 = (const float*)d_in[13];
  const float* m_w1_0 = (const float*)d_in[14];
  const float* m_b1_0 = (const float*)d_in[15];
  const float* m_w2_0 = (const float*)d_in[16];
  const float* m_b2_0 = (const float*)d_in[17];
  const float* w1_1 = (const float*)d_in[18];
  const float* b1_1 = (const float*)d_in[19];
  const float* w2_1 = (const float*)d_in[20];
  const float* b2_1 = (const float*)d_in[21];
  const float* m_w1_1 = (const float*)d_in[22];
  const float* m_b1_1 = (const float*)d_in[23];
  const float* m_w2_1 = (const float*)d_in[24];
  const float* m_b2_1 = (const float*)d_in[25];

  float* wsf = (float*)d_ws;
  unsigned long long* red = (unsigned long long*)d_ws;   // 98304 B of slots
  float* qbuf = wsf + 32768;
  float* kbuf = qbuf + NB*SEQ*HD;
  float* vbuf = kbuf + NB*SEQ*HD;
  float* thb  = vbuf + NB*SEQ*HD;
  float* alb  = thb + NB*SEQ;
  float* etb  = alb + NB*SEQ;
  // ws re-poisoned to 0xAA each launch; 0xAAAAAAAA is never a valid seq tag.

  qkv_kernel<<<dim3(NB*SEQ), dim3(HD), 0, stream>>>(
      x, Wq, Wk, Wv, w_lr, b_lr, w_fg, b_fg, w_mo, b_mo,
      qbuf, kbuf, vbuf, thb, alb, etb);

  scan_kernel<<<dim3(NB*NWG), dim3(512), 0, stream>>>(
      w1_0, b1_0, w2_0, b2_0, m_w1_0, m_b1_0, m_w2_0, m_b2_0,
      w1_1, b1_1, w2_1, b2_1, m_w1_1, m_b1_1, m_w2_1, m_b2_1,
      qbuf, kbuf, vbuf, thb, alb, etb,
      red, (float*)d_out);
}